// Round 13
// baseline (417.111 us; speedup 1.0000x reference)
//
#include <hip/hip_runtime.h>

// ---------------------------------------------------------------------------
// GCN encoder (4 conv layers, shared CSR graph) + 3-layer MLP decoder.
// Round 13: 3 decoder GEMMs + out-projection fused into one kernel (LDS
// round-trip, Ws restage W_sd->W_md); in_gemm folded into build_kernel.
// 11 launches total.
// ---------------------------------------------------------------------------

typedef __attribute__((ext_vector_type(8))) short short8;
typedef __attribute__((ext_vector_type(4))) float floatx4;
typedef __attribute__((ext_vector_type(2))) float floatx2;

#define BIN_CH 8192          // edges per bin block
#define NBMAX 512            // max buckets supported
#define HS_STRIDE 68         // LDS row stride in ushorts (136 B)

__device__ __forceinline__ unsigned short f2bf(float f) {
    unsigned int u = __float_as_uint(f);
    u += 0x7fffu + ((u >> 16) & 1u);          // round-to-nearest-even
    return (unsigned short)(u >> 16);
}
__device__ __forceinline__ unsigned int pk_bf(float a, float b) {
    return (unsigned int)f2bf(a) | ((unsigned int)f2bf(b) << 16);
}
__device__ __forceinline__ unsigned char f2fp8(float f) {
    return (unsigned char)(__builtin_amdgcn_cvt_pk_fp8_f32(f, f, 0, false) & 0xFF);
}
__device__ __forceinline__ short8 ld_frag(const unsigned short* p) {
    uint2 a = *(const uint2*)p;
    uint2 b = *(const uint2*)(p + 4);
    int4 v = make_int4((int)a.x, (int)a.y, (int)b.x, (int)b.y);
    return __builtin_bit_cast(short8, v);
}

// ---- weight pre-pack + buffer init (runs first) ---------------------------

__global__ void pack_kernel(const float* __restrict__ W0, const float* __restrict__ W1,
                            const float* __restrict__ W2, const float* __restrict__ W3,
                            unsigned short* __restrict__ P0, unsigned short* __restrict__ P1,
                            unsigned short* __restrict__ P2, unsigned short* __restrict__ P3,
                            int* __restrict__ gfill, unsigned char* __restrict__ t8zrow,
                            int NB) {
    if (blockIdx.x == 0) {                       // fold the memsets
        for (int i = threadIdx.x; i < NB; i += 256) gfill[i] = 0;
        if (threadIdx.x < 32) ((unsigned int*)t8zrow)[threadIdx.x] = 0;
    }
    int which = blockIdx.x >> 3;
    const float* W = which == 0 ? W0 : which == 1 ? W1 : which == 2 ? W2 : W3;
    unsigned short* P = which == 0 ? P0 : which == 1 ? P1 : which == 2 ? P2 : P3;
    int f = (blockIdx.x & 7) * 256 + threadIdx.x;
    int lane = f & 63, nt = (f >> 6) & 7, kc = f >> 9;
    int kbase = kc * 32 + (lane >> 4) * 8;
    int ncol = nt * 16 + (lane & 15);
    short8 frag;
    #pragma unroll
    for (int j = 0; j < 8; ++j)
        frag[j] = (short)f2bf(W[(size_t)(kbase + j) * 128 + ncol]);
    *((short8*)(P + (size_t)f * 8)) = frag;
}

// ---- graph build ----------------------------------------------------------

__global__ __launch_bounds__(512) void bin_kernel(
        const int* __restrict__ src, const int* __restrict__ dst,
        int* __restrict__ gfill, unsigned int* __restrict__ binbuf,
        int NB, int C, int E) {
    __shared__ int hist[NBMAX];
    __shared__ int start[NBMAX];
    __shared__ int dstoff[NBMAX];
    int tid = threadIdx.x;
    int e0 = blockIdx.x * BIN_CH;
    for (int i = tid; i < NB; i += 512) hist[i] = 0;
    __syncthreads();
    for (int i = tid; i < BIN_CH; i += 512) {
        int e = e0 + i;
        if (e < E) atomicAdd(&hist[dst[e] >> 9], 1);
    }
    __syncthreads();
    if (tid < 64) {
        int carry = 0;
        for (int base = 0; base < NB; base += 64) {
            int idx = base + tid;
            int v = (idx < NB) ? hist[idx] : 0;
            int s = v;
            #pragma unroll
            for (int off = 1; off < 64; off <<= 1) {
                int u = __shfl_up(s, off);
                if (tid >= off) s += u;
            }
            if (idx < NB) start[idx] = carry + s - v;
            carry += __shfl(s, 63);
        }
    }
    __syncthreads();
    for (int i = tid; i < NB; i += 512) {
        int cnt = hist[i];
        int g = cnt ? atomicAdd(&gfill[i], cnt) : 0;
        dstoff[i] = g - start[i];
        hist[i] = start[i];
    }
    __syncthreads();
    for (int i = tid; i < BIN_CH; i += 512) {
        int e = e0 + i;
        if (e >= E) continue;
        int d = dst[e];
        int b = d >> 9;
        int slot = atomicAdd(&hist[b], 1);
        int gidx = b * C + dstoff[b] + slot;
        if (gidx < (b + 1) * C)
            binbuf[gidx] = (unsigned int)src[e] | ((unsigned int)(d & 511) << 17);
    }
}

// one block per bucket: hist(512) -> scan -> rowptr/dinv -> place col ->
// in-place input layer: t8 rows = fp8(dinv * x @ W_s) for the bucket's nodes.
__global__ __launch_bounds__(256) void build_kernel(
        const unsigned int* __restrict__ binbuf, const int* __restrict__ gfill,
        const float* __restrict__ x, const float* __restrict__ W_s,
        int* __restrict__ rowptr, float* __restrict__ dinv, int* __restrict__ col,
        unsigned char* __restrict__ t8, int NB, int C, int N, int E) {
    __shared__ int h[512];
    __shared__ int hs[512];
    __shared__ int bbase_s;
    __shared__ float WsS[384];
    int b = blockIdx.x, tid = threadIdx.x;
    int cnt = gfill[b];
    const unsigned int* p = binbuf + (size_t)b * C;
    for (int i = tid; i < 512; i += 256) h[i] = 0;
    for (int i = tid; i < 384; i += 256) WsS[i] = W_s[i];
    __syncthreads();
    if (tid >= 64 && tid < 128) {          // wave 1: base = sum gfill[0..b)
        int l = tid - 64;
        int s = 0;
        for (int i = l; i < b; i += 64) s += gfill[i];
        #pragma unroll
        for (int off = 32; off > 0; off >>= 1) s += __shfl_down(s, off);
        if (l == 0) bbase_s = s;
    }
    for (int i = tid; i < cnt; i += 256) atomicAdd(&h[p[i] >> 17], 1);
    __syncthreads();
    if (tid < 64) {                        // wave 0: exclusive scan h->hs
        int carry = 0;
        for (int base = 0; base < 512; base += 64) {
            int v = h[base + tid];
            int s = v;
            #pragma unroll
            for (int off = 1; off < 64; off <<= 1) {
                int u = __shfl_up(s, off);
                if (tid >= off) s += u;
            }
            hs[base + tid] = carry + s - v;
            carry += __shfl(s, 63);
        }
    }
    __syncthreads();
    int base = bbase_s;
    for (int i = tid; i < 512; i += 256) {
        int node = b * 512 + i;
        if (node < N) {
            rowptr[node] = base + hs[i];
            dinv[node] = 1.0f / sqrtf((float)(h[i] + 1));
        }
    }
    if (b == 0 && tid == 0) rowptr[N] = E;
    __syncthreads();
    for (int i = tid; i < cnt; i += 256) {  // place (hs doubles as cursor)
        unsigned int u = p[i];
        int local = u >> 17;
        int pos = atomicAdd(&hs[local], 1);
        col[base + pos] = (int)(u & 0x1FFFFu);
    }
    // input layer for this bucket's nodes (h[] still holds counts)
    for (int idx = tid; idx < 512 * 64; idx += 256) {
        int il = idx >> 6, c2 = idx & 63;
        int node = b * 512 + il;
        if (node >= N) continue;
        float d = 1.0f / sqrtf((float)(h[il] + 1));
        float x0 = x[node * 3], x1 = x[node * 3 + 1], x2 = x[node * 3 + 2];
        int c = c2 * 2;
        float v0 = d * (x0 * WsS[c]     + x1 * WsS[128 + c]     + x2 * WsS[256 + c]);
        float v1 = d * (x0 * WsS[c + 1] + x1 * WsS[128 + c + 1] + x2 * WsS[256 + c + 1]);
        unsigned int pk = __builtin_amdgcn_cvt_pk_fp8_f32(v0, v1, 0, false);
        ((unsigned short*)t8)[(size_t)node * 64 + c2] = (unsigned short)(pk & 0xFFFF);
    }
}

// ---- aggregation: out_i = relu( d_i * (t'_i + sum_j t'_j) + b ) -----------
// Quarter-per-node; 32-edge rounds: 16 uint4 row-loads in flight per wave.

__global__ __launch_bounds__(256) void agg_kernel(
        const unsigned char* __restrict__ t8, const int* __restrict__ rowptr,
        const int* __restrict__ col, const float* __restrict__ dinv,
        const float* __restrict__ bias, unsigned short* __restrict__ out, int n) {
    int node = blockIdx.x * 16 + (threadIdx.x >> 4);
    int lane = threadIdx.x & 63;
    int q16 = lane >> 4;            // quarter (node) within wave
    int lq  = lane & 15;            // edge slot within half-round
    int oct = (lane >> 3) & 1;      // which of 2 rows this lane helps load
    int l8  = lane & 7;             // 16B chunk within row
    if (node >= n) node = n - 1;    // dup work in tail, benign
    floatx2 acc[8];                 // cols 16*l8 .. +16
    #pragma unroll
    for (int i = 0; i < 8; ++i) acc[i] = (floatx2){0.f, 0.f};

    int beg = rowptr[node];
    int deg = rowptr[node + 1] - beg;
    for (int base = 0; base < deg; base += 32) {
        int m = deg - base;
        int jv0 = (lq < m)      ? col[beg + base + lq]      : n;   // n = zero row
        int jv1 = (lq + 16 < m) ? col[beg + base + 16 + lq] : n;
        uint4 v[16];
        #pragma unroll
        for (int q = 0; q < 8; ++q) {
            int j = __shfl(jv0, q16 * 16 + q * 2 + oct);
            v[q] = ((const uint4*)(t8 + (size_t)j * 128))[l8];
        }
        #pragma unroll
        for (int q = 0; q < 8; ++q) {
            int j = __shfl(jv1, q16 * 16 + q * 2 + oct);
            v[8 + q] = ((const uint4*)(t8 + (size_t)j * 128))[l8];
        }
        #pragma unroll
        for (int q = 0; q < 16; ++q) {
            acc[0] += __builtin_amdgcn_cvt_pk_f32_fp8(v[q].x, false);
            acc[1] += __builtin_amdgcn_cvt_pk_f32_fp8(v[q].x, true);
            acc[2] += __builtin_amdgcn_cvt_pk_f32_fp8(v[q].y, false);
            acc[3] += __builtin_amdgcn_cvt_pk_f32_fp8(v[q].y, true);
            acc[4] += __builtin_amdgcn_cvt_pk_f32_fp8(v[q].z, false);
            acc[5] += __builtin_amdgcn_cvt_pk_f32_fp8(v[q].z, true);
            acc[6] += __builtin_amdgcn_cvt_pk_f32_fp8(v[q].w, false);
            acc[7] += __builtin_amdgcn_cvt_pk_f32_fp8(v[q].w, true);
        }
    }
    #pragma unroll
    for (int i = 0; i < 8; ++i) {
        acc[i].x += __shfl_xor(acc[i].x, 8);
        acc[i].y += __shfl_xor(acc[i].y, 8);
    }
    uint4 s = ((const uint4*)(t8 + (size_t)node * 128))[l8];
    acc[0] += __builtin_amdgcn_cvt_pk_f32_fp8(s.x, false);
    acc[1] += __builtin_amdgcn_cvt_pk_f32_fp8(s.x, true);
    acc[2] += __builtin_amdgcn_cvt_pk_f32_fp8(s.y, false);
    acc[3] += __builtin_amdgcn_cvt_pk_f32_fp8(s.y, true);
    acc[4] += __builtin_amdgcn_cvt_pk_f32_fp8(s.z, false);
    acc[5] += __builtin_amdgcn_cvt_pk_f32_fp8(s.z, true);
    acc[6] += __builtin_amdgcn_cvt_pk_f32_fp8(s.w, false);
    acc[7] += __builtin_amdgcn_cvt_pk_f32_fp8(s.w, true);

    float di = dinv[node];
    const float4* b4 = (const float4*)bias;     // cols 16*l8 .. +16
    float o[16];
    #pragma unroll
    for (int k = 0; k < 4; ++k) {
        float4 bb = b4[l8 * 4 + k];
        o[k*4+0] = fmaxf(di * acc[k*2].x   + bb.x, 0.f);
        o[k*4+1] = fmaxf(di * acc[k*2].y   + bb.y, 0.f);
        o[k*4+2] = fmaxf(di * acc[k*2+1].x + bb.z, 0.f);
        o[k*4+3] = fmaxf(di * acc[k*2+1].y + bb.w, 0.f);
    }
    if (oct == 0) {
        uint4 w0, w1;
        w0.x = pk_bf(o[0],  o[1]);  w0.y = pk_bf(o[2],  o[3]);
        w0.z = pk_bf(o[4],  o[5]);  w0.w = pk_bf(o[6],  o[7]);
        w1.x = pk_bf(o[8],  o[9]);  w1.y = pk_bf(o[10], o[11]);
        w1.z = pk_bf(o[12], o[13]); w1.w = pk_bf(o[14], o[15]);
        ((uint4*)(out + (size_t)node * 128))[l8 * 2]     = w0;
        ((uint4*)(out + (size_t)node * 128))[l8 * 2 + 1] = w1;
    }
}

// ---- shared GEMM pieces ---------------------------------------------------

__device__ __forceinline__ void stage_ws(unsigned short* Ws, const unsigned short* Wp, int tid) {
    const int4* s = (const int4*)Wp;
    int4* d = (int4*)Ws;
    #pragma unroll
    for (int i = 0; i < 8; ++i) d[tid + 256 * i] = s[tid + 256 * i];
}

__device__ __forceinline__ void gemm_regs(const short8 af[2][4], const unsigned short* Ws,
                                          int lane, floatx4 acc[2][8]) {
    #pragma unroll
    for (int t = 0; t < 2; ++t)
        #pragma unroll
        for (int nt = 0; nt < 8; ++nt) acc[t][nt] = (floatx4){0.f, 0.f, 0.f, 0.f};
    #pragma unroll
    for (int kc = 0; kc < 4; ++kc) {
        #pragma unroll
        for (int nt = 0; nt < 8; ++nt) {
            short8 bf = *((const short8*)(Ws + ((kc * 8 + nt) * 64 + lane) * 8));
            acc[0][nt] = __builtin_amdgcn_mfma_f32_16x16x32_bf16(af[0][kc], bf, acc[0][nt], 0, 0, 0);
            acc[1][nt] = __builtin_amdgcn_mfma_f32_16x16x32_bf16(af[1][kc], bf, acc[1][nt], 0, 0, 0);
        }
    }
}

__device__ __forceinline__ void gemm_lds(const unsigned short* Hs, const unsigned short* Ws,
                                         int wav, int lane, floatx4 acc[2][8]) {
    int quad = lane >> 4, mrow = lane & 15;
    short8 af[2][4];
    #pragma unroll
    for (int t = 0; t < 2; ++t)
        #pragma unroll
        for (int kc = 0; kc < 4; ++kc)
            af[t][kc] = ld_frag(Hs + (wav * 32 + t * 16 + mrow) * HS_STRIDE + (kc * 4 + quad) * 8);
    gemm_regs(af, Ws, lane, acc);
}

__device__ __forceinline__ void relu_store_hs(
        unsigned short* Hs, const float* __restrict__ bias,
        floatx4 acc[2][8], int wav, int lane) {
    int quad = lane >> 4, mrow = lane & 15;
    #pragma unroll
    for (int t = 0; t < 2; ++t) {
        #pragma unroll
        for (int nt = 0; nt < 8; ++nt) {
            int colc = nt * 16 + mrow;
            float bcol = bias[colc];
            #pragma unroll
            for (int r = 0; r < 4; ++r) {
                int rowl = wav * 32 + t * 16 + quad * 4 + r;
                Hs[rowl * HS_STRIDE + colc] = f2bf(fmaxf(acc[t][nt][r] + bcol, 0.f));
            }
        }
    }
}

// ---- encoder GEMM: t8 = fp8( dinv[row] * (A@W) ) --------------------------

__global__ __launch_bounds__(256) void gemm_enc_kernel(
        const unsigned short* __restrict__ A, const unsigned short* __restrict__ Wp,
        const float* __restrict__ dinv, unsigned char* __restrict__ outp, int n) {
    __shared__ unsigned short Ws[16384];
    int tid = threadIdx.x;
    stage_ws(Ws, Wp, tid);
    int wave = tid >> 6, lane = tid & 63;
    int quad = lane >> 4, mrow = lane & 15;
    int row0 = blockIdx.x * 128 + wave * 32;

    short8 af[2][4];
    #pragma unroll
    for (int t = 0; t < 2; ++t) {
        int arow = row0 + t * 16 + mrow; if (arow >= n) arow = n - 1;
        const unsigned short* abase = A + (size_t)arow * 128 + quad * 8;
        #pragma unroll
        for (int kc = 0; kc < 4; ++kc)
            af[t][kc] = *((const short8*)(abase + kc * 32));
    }
    __syncthreads();
    floatx4 acc[2][8];
    gemm_regs(af, Ws, lane, acc);

    #pragma unroll
    for (int t = 0; t < 2; ++t) {
        int rbase = row0 + t * 16 + quad * 4;
        float dv[4];
        #pragma unroll
        for (int r = 0; r < 4; ++r)
            dv[r] = (rbase + r < n) ? dinv[rbase + r] : 0.f;
        #pragma unroll
        for (int nt = 0; nt < 8; ++nt) {
            int colc = nt * 16 + mrow;
            #pragma unroll
            for (int r = 0; r < 4; ++r) {
                int row = rbase + r;
                if (row < n)
                    outp[(size_t)row * 128 + colc] = f2fp8(acc[t][nt][r] * dv[r]);
            }
        }
    }
}

// ---- fused decoder: GEMM(W_sd) -> GEMM(W_md) -> GEMM(W_md)+proj+residual --

__global__ __launch_bounds__(256) void decoder_kernel(
        const unsigned short* __restrict__ A,
        const unsigned short* __restrict__ Wp_sd, const float* __restrict__ b_sd,
        const unsigned short* __restrict__ Wp_md, const float* __restrict__ b_md,
        const float* __restrict__ W_ed, const float* __restrict__ b_ed,
        const float* __restrict__ x, float* __restrict__ out, int n) {
    __shared__ unsigned short Ws[16384];
    __shared__ unsigned short Hs[128 * HS_STRIDE];
    int tid = threadIdx.x;
    stage_ws(Ws, Wp_sd, tid);
    int wav = tid >> 6, lane = tid & 63;
    int quad = lane >> 4, mrow = lane & 15;
    int row0 = blockIdx.x * 128 + wav * 32;

    short8 af[2][4];
    #pragma unroll
    for (int t = 0; t < 2; ++t) {
        int arow = row0 + t * 16 + mrow; if (arow >= n) arow = n - 1;
        const unsigned short* abase = A + (size_t)arow * 128 + quad * 8;
        #pragma unroll
        for (int kc = 0; kc < 4; ++kc)
            af[t][kc] = *((const short8*)(abase + kc * 32));
    }
    __syncthreads();

    floatx4 acc[2][8];
    // stage 1: h @ W_sd
    gemm_regs(af, Ws, lane, acc);
    relu_store_hs(Hs, b_sd, acc, wav, lane);
    __syncthreads();                 // all waves done reading Ws
    stage_ws(Ws, Wp_md, tid);
    __syncthreads();
    // stage 2: @ W_md (Hs rows are wave-private -> no barrier around store)
    gemm_lds(Hs, Ws, wav, lane, acc);
    relu_store_hs(Hs, b_md, acc, wav, lane);
    // stage 3: @ W_md
    gemm_lds(Hs, Ws, wav, lane, acc);

    // out-projection: relu(acc+b_md) @ W_ed + b_ed + x
    float wed[8][3];
    #pragma unroll
    for (int nt = 0; nt < 8; ++nt) {
        int c = nt * 16 + mrow;
        #pragma unroll
        for (int k = 0; k < 3; ++k) wed[nt][k] = W_ed[c * 3 + k];
    }
    #pragma unroll
    for (int t = 0; t < 2; ++t) {
        #pragma unroll
        for (int r = 0; r < 4; ++r) {
            float s0 = 0.f, s1 = 0.f, s2 = 0.f;
            #pragma unroll
            for (int nt = 0; nt < 8; ++nt) {
                float v = fmaxf(acc[t][nt][r] + b_md[nt * 16 + mrow], 0.f);
                s0 += v * wed[nt][0]; s1 += v * wed[nt][1]; s2 += v * wed[nt][2];
            }
            #pragma unroll
            for (int off = 1; off < 16; off <<= 1) {
                s0 += __shfl_xor(s0, off);
                s1 += __shfl_xor(s1, off);
                s2 += __shfl_xor(s2, off);
            }
            if (mrow == 0) {
                int row = row0 + t * 16 + quad * 4 + r;
                if (row < n) {
                    out[row * 3 + 0] = s0 + b_ed[0] + x[row * 3 + 0];
                    out[row * 3 + 1] = s1 + b_ed[1] + x[row * 3 + 1];
                    out[row * 3 + 2] = s2 + b_ed[2] + x[row * 3 + 2];
                }
            }
        }
    }
}

// ---------------------------------------------------------------------------

extern "C" void kernel_launch(void* const* d_in, const int* in_sizes, int n_in,
                              void* d_out, int out_size, void* d_ws, size_t ws_size,
                              hipStream_t stream) {
    const float* x    = (const float*)d_in[0];
    const int*   ei   = (const int*)d_in[1];
    const float* W_s  = (const float*)d_in[2];
    const float* b_s  = (const float*)d_in[3];
    const float* W_m  = (const float*)d_in[4];
    const float* b_m  = (const float*)d_in[5];
    const float* W_e  = (const float*)d_in[6];
    const float* b_e  = (const float*)d_in[7];
    const float* W_sd = (const float*)d_in[8];
    const float* b_sd = (const float*)d_in[9];
    const float* W_md = (const float*)d_in[10];
    const float* b_md = (const float*)d_in[11];
    const float* W_ed = (const float*)d_in[12];
    const float* b_ed = (const float*)d_in[13];
    float* outp = (float*)d_out;

    const int N = in_sizes[0] / 3;
    const int E = in_sizes[1] / 2;
    const int* src = ei;
    const int* dst = ei + E;

    const int NB = (N + 511) >> 9;                       // 512-node buckets
    const int C  = (((E / NB) * 3 / 2) + 255) & ~255;    // segment cap, 1.5x mean

    char* p = (char*)d_ws;
    auto carve = [&](size_t bytes) {
        void* r = (void*)p;
        p += (bytes + 255) & ~(size_t)255;
        return r;
    };
    int*   rowptr = (int*)  carve((size_t)(N + 1) * 4);
    int*   col    = (int*)  carve((size_t)E * 4);
    float* dinv   = (float*)carve((size_t)N * 4);
    int*   gfill  = (int*)  carve((size_t)NB * 4);
    unsigned int* binbuf = (unsigned int*)carve((size_t)NB * C * 4);
    unsigned short* Wp_m  = (unsigned short*)carve(16384 * 2);
    unsigned short* Wp_e  = (unsigned short*)carve(16384 * 2);
    unsigned short* Wp_sd = (unsigned short*)carve(16384 * 2);
    unsigned short* Wp_md = (unsigned short*)carve(16384 * 2);
    unsigned char*  T8 = (unsigned char*) carve((size_t)(N + 1) * 128);   // +1 zero row
    unsigned short* A  = (unsigned short*)carve((size_t)N * 128 * 2);
    (void)ws_size;

    const int gBin = (E + BIN_CH - 1) / BIN_CH;
    const int gNode16 = (N + 15) / 16;
    const int gRow128 = (N + 127) / 128;

    // weight packs + buffer init (no deps)
    pack_kernel<<<32, 256, 0, stream>>>(W_m, W_e, W_sd, W_md, Wp_m, Wp_e, Wp_sd, Wp_md,
                                        gfill, T8 + (size_t)N * 128, NB);

    // graph build (+ fused input layer)
    bin_kernel<<<gBin, 512, 0, stream>>>(src, dst, gfill, binbuf, NB, C, E);
    build_kernel<<<NB, 256, 0, stream>>>(binbuf, gfill, x, W_s, rowptr, dinv, col, T8,
                                         NB, C, N, E);

    // encoder (t' in fp8, h in bf16)
    agg_kernel<<<gNode16, 256, 0, stream>>>(T8, rowptr, col, dinv, b_s, A, N);
    gemm_enc_kernel<<<gRow128, 256, 0, stream>>>(A, Wp_m, dinv, T8, N);
    agg_kernel<<<gNode16, 256, 0, stream>>>(T8, rowptr, col, dinv, b_m, A, N);
    gemm_enc_kernel<<<gRow128, 256, 0, stream>>>(A, Wp_m, dinv, T8, N);
    agg_kernel<<<gNode16, 256, 0, stream>>>(T8, rowptr, col, dinv, b_m, A, N);
    gemm_enc_kernel<<<gRow128, 256, 0, stream>>>(A, Wp_e, dinv, T8, N);
    agg_kernel<<<gNode16, 256, 0, stream>>>(T8, rowptr, col, dinv, b_e, A, N);

    // fused decoder
    decoder_kernel<<<gRow128, 256, 0, stream>>>(A, Wp_sd, b_sd, Wp_md, b_md,
                                                W_ed, b_ed, x, outp, N);
}

// Round 14
// 398.773 us; speedup vs baseline: 1.0460x; 1.0460x over previous
//
#include <hip/hip_runtime.h>

// ---------------------------------------------------------------------------
// GCN encoder (4 conv layers, shared CSR graph) + 3-layer MLP decoder.
// Round 14: revert round-13's in_gemm->build fold (parallelism mismatch:
// build has only NB blocks). Keep fused decoder (win). 12 launches.
// ---------------------------------------------------------------------------

typedef __attribute__((ext_vector_type(8))) short short8;
typedef __attribute__((ext_vector_type(4))) float floatx4;
typedef __attribute__((ext_vector_type(2))) float floatx2;

#define BIN_CH 8192          // edges per bin block
#define NBMAX 512            // max buckets supported
#define HS_STRIDE 68         // LDS row stride in ushorts (136 B)

__device__ __forceinline__ unsigned short f2bf(float f) {
    unsigned int u = __float_as_uint(f);
    u += 0x7fffu + ((u >> 16) & 1u);          // round-to-nearest-even
    return (unsigned short)(u >> 16);
}
__device__ __forceinline__ unsigned int pk_bf(float a, float b) {
    return (unsigned int)f2bf(a) | ((unsigned int)f2bf(b) << 16);
}
__device__ __forceinline__ unsigned char f2fp8(float f) {
    return (unsigned char)(__builtin_amdgcn_cvt_pk_fp8_f32(f, f, 0, false) & 0xFF);
}
__device__ __forceinline__ short8 ld_frag(const unsigned short* p) {
    uint2 a = *(const uint2*)p;
    uint2 b = *(const uint2*)(p + 4);
    int4 v = make_int4((int)a.x, (int)a.y, (int)b.x, (int)b.y);
    return __builtin_bit_cast(short8, v);
}

// ---- weight pre-pack + buffer init (runs first) ---------------------------

__global__ void pack_kernel(const float* __restrict__ W0, const float* __restrict__ W1,
                            const float* __restrict__ W2, const float* __restrict__ W3,
                            unsigned short* __restrict__ P0, unsigned short* __restrict__ P1,
                            unsigned short* __restrict__ P2, unsigned short* __restrict__ P3,
                            int* __restrict__ gfill, unsigned char* __restrict__ t8zrow,
                            int NB) {
    if (blockIdx.x == 0) {                       // fold the memsets
        for (int i = threadIdx.x; i < NB; i += 256) gfill[i] = 0;
        if (threadIdx.x < 32) ((unsigned int*)t8zrow)[threadIdx.x] = 0;
    }
    int which = blockIdx.x >> 3;
    const float* W = which == 0 ? W0 : which == 1 ? W1 : which == 2 ? W2 : W3;
    unsigned short* P = which == 0 ? P0 : which == 1 ? P1 : which == 2 ? P2 : P3;
    int f = (blockIdx.x & 7) * 256 + threadIdx.x;
    int lane = f & 63, nt = (f >> 6) & 7, kc = f >> 9;
    int kbase = kc * 32 + (lane >> 4) * 8;
    int ncol = nt * 16 + (lane & 15);
    short8 frag;
    #pragma unroll
    for (int j = 0; j < 8; ++j)
        frag[j] = (short)f2bf(W[(size_t)(kbase + j) * 128 + ncol]);
    *((short8*)(P + (size_t)f * 8)) = frag;
}

// ---- graph build ----------------------------------------------------------

__global__ __launch_bounds__(512) void bin_kernel(
        const int* __restrict__ src, const int* __restrict__ dst,
        int* __restrict__ gfill, unsigned int* __restrict__ binbuf,
        int NB, int C, int E) {
    __shared__ int hist[NBMAX];
    __shared__ int start[NBMAX];
    __shared__ int dstoff[NBMAX];
    int tid = threadIdx.x;
    int e0 = blockIdx.x * BIN_CH;
    for (int i = tid; i < NB; i += 512) hist[i] = 0;
    __syncthreads();
    for (int i = tid; i < BIN_CH; i += 512) {
        int e = e0 + i;
        if (e < E) atomicAdd(&hist[dst[e] >> 9], 1);
    }
    __syncthreads();
    if (tid < 64) {
        int carry = 0;
        for (int base = 0; base < NB; base += 64) {
            int idx = base + tid;
            int v = (idx < NB) ? hist[idx] : 0;
            int s = v;
            #pragma unroll
            for (int off = 1; off < 64; off <<= 1) {
                int u = __shfl_up(s, off);
                if (tid >= off) s += u;
            }
            if (idx < NB) start[idx] = carry + s - v;
            carry += __shfl(s, 63);
        }
    }
    __syncthreads();
    for (int i = tid; i < NB; i += 512) {
        int cnt = hist[i];
        int g = cnt ? atomicAdd(&gfill[i], cnt) : 0;
        dstoff[i] = g - start[i];
        hist[i] = start[i];
    }
    __syncthreads();
    for (int i = tid; i < BIN_CH; i += 512) {
        int e = e0 + i;
        if (e >= E) continue;
        int d = dst[e];
        int b = d >> 9;
        int slot = atomicAdd(&hist[b], 1);
        int gidx = b * C + dstoff[b] + slot;
        if (gidx < (b + 1) * C)
            binbuf[gidx] = (unsigned int)src[e] | ((unsigned int)(d & 511) << 17);
    }
}

// one block per bucket: hist(512) -> scan -> rowptr/dinv -> place col.
// Bucket base computed in-kernel (wave 1 sums gfill[0..b)).
__global__ __launch_bounds__(256) void build_kernel(
        const unsigned int* __restrict__ binbuf, const int* __restrict__ gfill,
        int* __restrict__ rowptr, float* __restrict__ dinv, int* __restrict__ col,
        int NB, int C, int N, int E) {
    __shared__ int h[512];
    __shared__ int hs[512];
    __shared__ int bbase_s;
    int b = blockIdx.x, tid = threadIdx.x;
    int cnt = gfill[b];
    const unsigned int* p = binbuf + (size_t)b * C;
    for (int i = tid; i < 512; i += 256) h[i] = 0;
    __syncthreads();
    if (tid >= 64 && tid < 128) {          // wave 1: base = sum gfill[0..b)
        int l = tid - 64;
        int s = 0;
        for (int i = l; i < b; i += 64) s += gfill[i];
        #pragma unroll
        for (int off = 32; off > 0; off >>= 1) s += __shfl_down(s, off);
        if (l == 0) bbase_s = s;
    }
    for (int i = tid; i < cnt; i += 256) atomicAdd(&h[p[i] >> 17], 1);
    __syncthreads();
    if (tid < 64) {                        // wave 0: exclusive scan h->hs
        int carry = 0;
        for (int base = 0; base < 512; base += 64) {
            int v = h[base + tid];
            int s = v;
            #pragma unroll
            for (int off = 1; off < 64; off <<= 1) {
                int u = __shfl_up(s, off);
                if (tid >= off) s += u;
            }
            hs[base + tid] = carry + s - v;
            carry += __shfl(s, 63);
        }
    }
    __syncthreads();
    int base = bbase_s;
    for (int i = tid; i < 512; i += 256) {
        int node = b * 512 + i;
        if (node < N) {
            rowptr[node] = base + hs[i];
            dinv[node] = 1.0f / sqrtf((float)(h[i] + 1));
        }
    }
    if (b == 0 && tid == 0) rowptr[N] = E;
    __syncthreads();
    for (int i = tid; i < cnt; i += 256) {  // place (hs doubles as cursor)
        unsigned int u = p[i];
        int local = u >> 17;
        int pos = atomicAdd(&hs[local], 1);
        col[base + pos] = (int)(u & 0x1FFFFu);
    }
}

// ---- input layer: t' = fp8( dinv_i * (x @ W_s) ) --------------------------

__global__ void in_gemm_kernel(const float* __restrict__ x, const float* __restrict__ W,
                               const float* __restrict__ dinv,
                               unsigned char* __restrict__ t8, int n) {
    int g = blockIdx.x * 256 + threadIdx.x;
    int i = g >> 6, c2 = g & 63;
    if (i >= n) return;
    float x0 = x[i * 3], x1 = x[i * 3 + 1], x2 = x[i * 3 + 2];
    float d = dinv[i];
    int c = c2 * 2;
    float v0 = d * (x0 * W[c]     + x1 * W[128 + c]     + x2 * W[256 + c]);
    float v1 = d * (x0 * W[c + 1] + x1 * W[128 + c + 1] + x2 * W[256 + c + 1]);
    unsigned int pk = __builtin_amdgcn_cvt_pk_fp8_f32(v0, v1, 0, false);
    ((unsigned short*)t8)[(size_t)i * 64 + c2] = (unsigned short)(pk & 0xFFFF);
}

// ---- aggregation: out_i = relu( d_i * (t'_i + sum_j t'_j) + b ) -----------
// Quarter-per-node; 32-edge rounds: 16 uint4 row-loads in flight per wave.

__global__ __launch_bounds__(256) void agg_kernel(
        const unsigned char* __restrict__ t8, const int* __restrict__ rowptr,
        const int* __restrict__ col, const float* __restrict__ dinv,
        const float* __restrict__ bias, unsigned short* __restrict__ out, int n) {
    int node = blockIdx.x * 16 + (threadIdx.x >> 4);
    int lane = threadIdx.x & 63;
    int q16 = lane >> 4;            // quarter (node) within wave
    int lq  = lane & 15;            // edge slot within half-round
    int oct = (lane >> 3) & 1;      // which of 2 rows this lane helps load
    int l8  = lane & 7;             // 16B chunk within row
    if (node >= n) node = n - 1;    // dup work in tail, benign
    floatx2 acc[8];                 // cols 16*l8 .. +16
    #pragma unroll
    for (int i = 0; i < 8; ++i) acc[i] = (floatx2){0.f, 0.f};

    int beg = rowptr[node];
    int deg = rowptr[node + 1] - beg;
    for (int base = 0; base < deg; base += 32) {
        int m = deg - base;
        int jv0 = (lq < m)      ? col[beg + base + lq]      : n;   // n = zero row
        int jv1 = (lq + 16 < m) ? col[beg + base + 16 + lq] : n;
        uint4 v[16];
        #pragma unroll
        for (int q = 0; q < 8; ++q) {
            int j = __shfl(jv0, q16 * 16 + q * 2 + oct);
            v[q] = ((const uint4*)(t8 + (size_t)j * 128))[l8];
        }
        #pragma unroll
        for (int q = 0; q < 8; ++q) {
            int j = __shfl(jv1, q16 * 16 + q * 2 + oct);
            v[8 + q] = ((const uint4*)(t8 + (size_t)j * 128))[l8];
        }
        #pragma unroll
        for (int q = 0; q < 16; ++q) {
            acc[0] += __builtin_amdgcn_cvt_pk_f32_fp8(v[q].x, false);
            acc[1] += __builtin_amdgcn_cvt_pk_f32_fp8(v[q].x, true);
            acc[2] += __builtin_amdgcn_cvt_pk_f32_fp8(v[q].y, false);
            acc[3] += __builtin_amdgcn_cvt_pk_f32_fp8(v[q].y, true);
            acc[4] += __builtin_amdgcn_cvt_pk_f32_fp8(v[q].z, false);
            acc[5] += __builtin_amdgcn_cvt_pk_f32_fp8(v[q].z, true);
            acc[6] += __builtin_amdgcn_cvt_pk_f32_fp8(v[q].w, false);
            acc[7] += __builtin_amdgcn_cvt_pk_f32_fp8(v[q].w, true);
        }
    }
    #pragma unroll
    for (int i = 0; i < 8; ++i) {
        acc[i].x += __shfl_xor(acc[i].x, 8);
        acc[i].y += __shfl_xor(acc[i].y, 8);
    }
    uint4 s = ((const uint4*)(t8 + (size_t)node * 128))[l8];
    acc[0] += __builtin_amdgcn_cvt_pk_f32_fp8(s.x, false);
    acc[1] += __builtin_amdgcn_cvt_pk_f32_fp8(s.x, true);
    acc[2] += __builtin_amdgcn_cvt_pk_f32_fp8(s.y, false);
    acc[3] += __builtin_amdgcn_cvt_pk_f32_fp8(s.y, true);
    acc[4] += __builtin_amdgcn_cvt_pk_f32_fp8(s.z, false);
    acc[5] += __builtin_amdgcn_cvt_pk_f32_fp8(s.z, true);
    acc[6] += __builtin_amdgcn_cvt_pk_f32_fp8(s.w, false);
    acc[7] += __builtin_amdgcn_cvt_pk_f32_fp8(s.w, true);

    float di = dinv[node];
    const float4* b4 = (const float4*)bias;     // cols 16*l8 .. +16
    float o[16];
    #pragma unroll
    for (int k = 0; k < 4; ++k) {
        float4 bb = b4[l8 * 4 + k];
        o[k*4+0] = fmaxf(di * acc[k*2].x   + bb.x, 0.f);
        o[k*4+1] = fmaxf(di * acc[k*2].y   + bb.y, 0.f);
        o[k*4+2] = fmaxf(di * acc[k*2+1].x + bb.z, 0.f);
        o[k*4+3] = fmaxf(di * acc[k*2+1].y + bb.w, 0.f);
    }
    if (oct == 0) {
        uint4 w0, w1;
        w0.x = pk_bf(o[0],  o[1]);  w0.y = pk_bf(o[2],  o[3]);
        w0.z = pk_bf(o[4],  o[5]);  w0.w = pk_bf(o[6],  o[7]);
        w1.x = pk_bf(o[8],  o[9]);  w1.y = pk_bf(o[10], o[11]);
        w1.z = pk_bf(o[12], o[13]); w1.w = pk_bf(o[14], o[15]);
        ((uint4*)(out + (size_t)node * 128))[l8 * 2]     = w0;
        ((uint4*)(out + (size_t)node * 128))[l8 * 2 + 1] = w1;
    }
}

// ---- shared GEMM pieces ---------------------------------------------------

__device__ __forceinline__ void stage_ws(unsigned short* Ws, const unsigned short* Wp, int tid) {
    const int4* s = (const int4*)Wp;
    int4* d = (int4*)Ws;
    #pragma unroll
    for (int i = 0; i < 8; ++i) d[tid + 256 * i] = s[tid + 256 * i];
}

__device__ __forceinline__ void gemm_regs(const short8 af[2][4], const unsigned short* Ws,
                                          int lane, floatx4 acc[2][8]) {
    #pragma unroll
    for (int t = 0; t < 2; ++t)
        #pragma unroll
        for (int nt = 0; nt < 8; ++nt) acc[t][nt] = (floatx4){0.f, 0.f, 0.f, 0.f};
    #pragma unroll
    for (int kc = 0; kc < 4; ++kc) {
        #pragma unroll
        for (int nt = 0; nt < 8; ++nt) {
            short8 bf = *((const short8*)(Ws + ((kc * 8 + nt) * 64 + lane) * 8));
            acc[0][nt] = __builtin_amdgcn_mfma_f32_16x16x32_bf16(af[0][kc], bf, acc[0][nt], 0, 0, 0);
            acc[1][nt] = __builtin_amdgcn_mfma_f32_16x16x32_bf16(af[1][kc], bf, acc[1][nt], 0, 0, 0);
        }
    }
}

__device__ __forceinline__ void gemm_lds(const unsigned short* Hs, const unsigned short* Ws,
                                         int wav, int lane, floatx4 acc[2][8]) {
    int quad = lane >> 4, mrow = lane & 15;
    short8 af[2][4];
    #pragma unroll
    for (int t = 0; t < 2; ++t)
        #pragma unroll
        for (int kc = 0; kc < 4; ++kc)
            af[t][kc] = ld_frag(Hs + (wav * 32 + t * 16 + mrow) * HS_STRIDE + (kc * 4 + quad) * 8);
    gemm_regs(af, Ws, lane, acc);
}

__device__ __forceinline__ void relu_store_hs(
        unsigned short* Hs, const float* __restrict__ bias,
        floatx4 acc[2][8], int wav, int lane) {
    int quad = lane >> 4, mrow = lane & 15;
    #pragma unroll
    for (int t = 0; t < 2; ++t) {
        #pragma unroll
        for (int nt = 0; nt < 8; ++nt) {
            int colc = nt * 16 + mrow;
            float bcol = bias[colc];
            #pragma unroll
            for (int r = 0; r < 4; ++r) {
                int rowl = wav * 32 + t * 16 + quad * 4 + r;
                Hs[rowl * HS_STRIDE + colc] = f2bf(fmaxf(acc[t][nt][r] + bcol, 0.f));
            }
        }
    }
}

// ---- encoder GEMM: t8 = fp8( dinv[row] * (A@W) ) --------------------------

__global__ __launch_bounds__(256) void gemm_enc_kernel(
        const unsigned short* __restrict__ A, const unsigned short* __restrict__ Wp,
        const float* __restrict__ dinv, unsigned char* __restrict__ outp, int n) {
    __shared__ unsigned short Ws[16384];
    int tid = threadIdx.x;
    stage_ws(Ws, Wp, tid);
    int wave = tid >> 6, lane = tid & 63;
    int quad = lane >> 4, mrow = lane & 15;
    int row0 = blockIdx.x * 128 + wave * 32;

    short8 af[2][4];
    #pragma unroll
    for (int t = 0; t < 2; ++t) {
        int arow = row0 + t * 16 + mrow; if (arow >= n) arow = n - 1;
        const unsigned short* abase = A + (size_t)arow * 128 + quad * 8;
        #pragma unroll
        for (int kc = 0; kc < 4; ++kc)
            af[t][kc] = *((const short8*)(abase + kc * 32));
    }
    __syncthreads();
    floatx4 acc[2][8];
    gemm_regs(af, Ws, lane, acc);

    #pragma unroll
    for (int t = 0; t < 2; ++t) {
        int rbase = row0 + t * 16 + quad * 4;
        float dv[4];
        #pragma unroll
        for (int r = 0; r < 4; ++r)
            dv[r] = (rbase + r < n) ? dinv[rbase + r] : 0.f;
        #pragma unroll
        for (int nt = 0; nt < 8; ++nt) {
            int colc = nt * 16 + mrow;
            #pragma unroll
            for (int r = 0; r < 4; ++r) {
                int row = rbase + r;
                if (row < n)
                    outp[(size_t)row * 128 + colc] = f2fp8(acc[t][nt][r] * dv[r]);
            }
        }
    }
}

// ---- fused decoder: GEMM(W_sd) -> GEMM(W_md) -> GEMM(W_md)+proj+residual --

__global__ __launch_bounds__(256) void decoder_kernel(
        const unsigned short* __restrict__ A,
        const unsigned short* __restrict__ Wp_sd, const float* __restrict__ b_sd,
        const unsigned short* __restrict__ Wp_md, const float* __restrict__ b_md,
        const float* __restrict__ W_ed, const float* __restrict__ b_ed,
        const float* __restrict__ x, float* __restrict__ out, int n) {
    __shared__ unsigned short Ws[16384];
    __shared__ unsigned short Hs[128 * HS_STRIDE];
    int tid = threadIdx.x;
    stage_ws(Ws, Wp_sd, tid);
    int wav = tid >> 6, lane = tid & 63;
    int quad = lane >> 4, mrow = lane & 15;
    int row0 = blockIdx.x * 128 + wav * 32;

    short8 af[2][4];
    #pragma unroll
    for (int t = 0; t < 2; ++t) {
        int arow = row0 + t * 16 + mrow; if (arow >= n) arow = n - 1;
        const unsigned short* abase = A + (size_t)arow * 128 + quad * 8;
        #pragma unroll
        for (int kc = 0; kc < 4; ++kc)
            af[t][kc] = *((const short8*)(abase + kc * 32));
    }
    __syncthreads();

    floatx4 acc[2][8];
    // stage 1: h @ W_sd
    gemm_regs(af, Ws, lane, acc);
    relu_store_hs(Hs, b_sd, acc, wav, lane);
    __syncthreads();                 // all waves done reading Ws
    stage_ws(Ws, Wp_md, tid);
    __syncthreads();
    // stage 2: @ W_md (Hs rows are wave-private -> no barrier around store)
    gemm_lds(Hs, Ws, wav, lane, acc);
    relu_store_hs(Hs, b_md, acc, wav, lane);
    // stage 3: @ W_md
    gemm_lds(Hs, Ws, wav, lane, acc);

    // out-projection: relu(acc+b_md) @ W_ed + b_ed + x
    float wed[8][3];
    #pragma unroll
    for (int nt = 0; nt < 8; ++nt) {
        int c = nt * 16 + mrow;
        #pragma unroll
        for (int k = 0; k < 3; ++k) wed[nt][k] = W_ed[c * 3 + k];
    }
    #pragma unroll
    for (int t = 0; t < 2; ++t) {
        #pragma unroll
        for (int r = 0; r < 4; ++r) {
            float s0 = 0.f, s1 = 0.f, s2 = 0.f;
            #pragma unroll
            for (int nt = 0; nt < 8; ++nt) {
                float v = fmaxf(acc[t][nt][r] + b_md[nt * 16 + mrow], 0.f);
                s0 += v * wed[nt][0]; s1 += v * wed[nt][1]; s2 += v * wed[nt][2];
            }
            #pragma unroll
            for (int off = 1; off < 16; off <<= 1) {
                s0 += __shfl_xor(s0, off);
                s1 += __shfl_xor(s1, off);
                s2 += __shfl_xor(s2, off);
            }
            if (mrow == 0) {
                int row = row0 + t * 16 + quad * 4 + r;
                if (row < n) {
                    out[row * 3 + 0] = s0 + b_ed[0] + x[row * 3 + 0];
                    out[row * 3 + 1] = s1 + b_ed[1] + x[row * 3 + 1];
                    out[row * 3 + 2] = s2 + b_ed[2] + x[row * 3 + 2];
                }
            }
        }
    }
}

// ---------------------------------------------------------------------------

extern "C" void kernel_launch(void* const* d_in, const int* in_sizes, int n_in,
                              void* d_out, int out_size, void* d_ws, size_t ws_size,
                              hipStream_t stream) {
    const float* x    = (const float*)d_in[0];
    const int*   ei   = (const int*)d_in[1];
    const float* W_s  = (const float*)d_in[2];
    const float* b_s  = (const float*)d_in[3];
    const float* W_m  = (const float*)d_in[4];
    const float* b_m  = (const float*)d_in[5];
    const float* W_e  = (const float*)d_in[6];
    const float* b_e  = (const float*)d_in[7];
    const float* W_sd = (const float*)d_in[8];
    const float* b_sd = (const float*)d_in[9];
    const float* W_md = (const float*)d_in[10];
    const float* b_md = (const float*)d_in[11];
    const float* W_ed = (const float*)d_in[12];
    const float* b_ed = (const float*)d_in[13];
    float* outp = (float*)d_out;

    const int N = in_sizes[0] / 3;
    const int E = in_sizes[1] / 2;
    const int* src = ei;
    const int* dst = ei + E;

    const int NB = (N + 511) >> 9;                       // 512-node buckets
    const int C  = (((E / NB) * 3 / 2) + 255) & ~255;    // segment cap, 1.5x mean

    char* p = (char*)d_ws;
    auto carve = [&](size_t bytes) {
        void* r = (void*)p;
        p += (bytes + 255) & ~(size_t)255;
        return r;
    };
    int*   rowptr = (int*)  carve((size_t)(N + 1) * 4);
    int*   col    = (int*)  carve((size_t)E * 4);
    float* dinv   = (float*)carve((size_t)N * 4);
    int*   gfill  = (int*)  carve((size_t)NB * 4);
    unsigned int* binbuf = (unsigned int*)carve((size_t)NB * C * 4);
    unsigned short* Wp_m  = (unsigned short*)carve(16384 * 2);
    unsigned short* Wp_e  = (unsigned short*)carve(16384 * 2);
    unsigned short* Wp_sd = (unsigned short*)carve(16384 * 2);
    unsigned short* Wp_md = (unsigned short*)carve(16384 * 2);
    unsigned char*  T8 = (unsigned char*) carve((size_t)(N + 1) * 128);   // +1 zero row
    unsigned short* A  = (unsigned short*)carve((size_t)N * 128 * 2);
    (void)ws_size;

    const int gBin = (E + BIN_CH - 1) / BIN_CH;
    const int gNode16 = (N + 15) / 16;
    const int gRow128 = (N + 127) / 128;

    // weight packs + buffer init (no deps)
    pack_kernel<<<32, 256, 0, stream>>>(W_m, W_e, W_sd, W_md, Wp_m, Wp_e, Wp_sd, Wp_md,
                                        gfill, T8 + (size_t)N * 128, NB);

    // graph build
    bin_kernel<<<gBin, 512, 0, stream>>>(src, dst, gfill, binbuf, NB, C, E);
    build_kernel<<<NB, 256, 0, stream>>>(binbuf, gfill, rowptr, dinv, col, NB, C, N, E);

    // encoder (t' in fp8, h in bf16)
    in_gemm_kernel<<<(N * 64 + 255) / 256, 256, 0, stream>>>(x, W_s, dinv, T8, N);
    agg_kernel<<<gNode16, 256, 0, stream>>>(T8, rowptr, col, dinv, b_s, A, N);
    gemm_enc_kernel<<<gRow128, 256, 0, stream>>>(A, Wp_m, dinv, T8, N);
    agg_kernel<<<gNode16, 256, 0, stream>>>(T8, rowptr, col, dinv, b_m, A, N);
    gemm_enc_kernel<<<gRow128, 256, 0, stream>>>(A, Wp_m, dinv, T8, N);
    agg_kernel<<<gNode16, 256, 0, stream>>>(T8, rowptr, col, dinv, b_m, A, N);
    gemm_enc_kernel<<<gRow128, 256, 0, stream>>>(A, Wp_e, dinv, T8, N);
    agg_kernel<<<gNode16, 256, 0, stream>>>(T8, rowptr, col, dinv, b_e, A, N);

    // fused decoder
    decoder_kernel<<<gRow128, 256, 0, stream>>>(A, Wp_sd, b_sd, Wp_md, b_md,
                                                W_ed, b_ed, x, outp, N);
}

// Round 15
// 398.202 us; speedup vs baseline: 1.0475x; 1.0014x over previous
//
#include <hip/hip_runtime.h>

// ---------------------------------------------------------------------------
// GCN encoder (4 conv layers, shared CSR graph) + 3-layer MLP decoder.
// Round 15: per-wave-group split LDS histograms + cursors in bin/build
// (4x less same-address LDS atomic contention). Rest = round 14.
// ---------------------------------------------------------------------------

typedef __attribute__((ext_vector_type(8))) short short8;
typedef __attribute__((ext_vector_type(4))) float floatx4;
typedef __attribute__((ext_vector_type(2))) float floatx2;

#define BIN_CH 8192          // edges per bin block
#define NBMAX 512            // max buckets supported
#define HS_STRIDE 68         // LDS row stride in ushorts (136 B)

__device__ __forceinline__ unsigned short f2bf(float f) {
    unsigned int u = __float_as_uint(f);
    u += 0x7fffu + ((u >> 16) & 1u);          // round-to-nearest-even
    return (unsigned short)(u >> 16);
}
__device__ __forceinline__ unsigned int pk_bf(float a, float b) {
    return (unsigned int)f2bf(a) | ((unsigned int)f2bf(b) << 16);
}
__device__ __forceinline__ unsigned char f2fp8(float f) {
    return (unsigned char)(__builtin_amdgcn_cvt_pk_fp8_f32(f, f, 0, false) & 0xFF);
}
__device__ __forceinline__ short8 ld_frag(const unsigned short* p) {
    uint2 a = *(const uint2*)p;
    uint2 b = *(const uint2*)(p + 4);
    int4 v = make_int4((int)a.x, (int)a.y, (int)b.x, (int)b.y);
    return __builtin_bit_cast(short8, v);
}

// ---- weight pre-pack + buffer init (runs first) ---------------------------

__global__ void pack_kernel(const float* __restrict__ W0, const float* __restrict__ W1,
                            const float* __restrict__ W2, const float* __restrict__ W3,
                            unsigned short* __restrict__ P0, unsigned short* __restrict__ P1,
                            unsigned short* __restrict__ P2, unsigned short* __restrict__ P3,
                            int* __restrict__ gfill, unsigned char* __restrict__ t8zrow,
                            int NB) {
    if (blockIdx.x == 0) {                       // fold the memsets
        for (int i = threadIdx.x; i < NB; i += 256) gfill[i] = 0;
        if (threadIdx.x < 32) ((unsigned int*)t8zrow)[threadIdx.x] = 0;
    }
    int which = blockIdx.x >> 3;
    const float* W = which == 0 ? W0 : which == 1 ? W1 : which == 2 ? W2 : W3;
    unsigned short* P = which == 0 ? P0 : which == 1 ? P1 : which == 2 ? P2 : P3;
    int f = (blockIdx.x & 7) * 256 + threadIdx.x;
    int lane = f & 63, nt = (f >> 6) & 7, kc = f >> 9;
    int kbase = kc * 32 + (lane >> 4) * 8;
    int ncol = nt * 16 + (lane & 15);
    short8 frag;
    #pragma unroll
    for (int j = 0; j < 8; ++j)
        frag[j] = (short)f2bf(W[(size_t)(kbase + j) * 128 + ncol]);
    *((short8*)(P + (size_t)f * 8)) = frag;
}

// ---- graph build ----------------------------------------------------------
// 4 split histograms (tid>>7 groups of 128 threads) cut LDS atomic
// contention 4x in both the count and the place-cursor loops.

__global__ __launch_bounds__(512) void bin_kernel(
        const int* __restrict__ src, const int* __restrict__ dst,
        int* __restrict__ gfill, unsigned int* __restrict__ binbuf,
        int NB, int C, int E) {
    __shared__ int h4[4][NBMAX];     // per-group counts -> cursors
    __shared__ int start[NBMAX];
    __shared__ int tot[NBMAX];
    __shared__ int dstoff[NBMAX];
    int tid = threadIdx.x;
    int grp = tid >> 7;
    int e0 = blockIdx.x * BIN_CH;
    for (int i = tid; i < 4 * NBMAX; i += 512) ((int*)h4)[i] = 0;
    __syncthreads();
    for (int i = tid; i < BIN_CH; i += 512) {
        int e = e0 + i;
        if (e < E) atomicAdd(&h4[grp][dst[e] >> 9], 1);
    }
    __syncthreads();
    if (tid < 64) {        // wave 0: totals, exclusive scan, per-group bases
        int carry = 0;
        for (int base = 0; base < NB; base += 64) {
            int idx = base + tid;
            int c0 = 0, c1 = 0, c2 = 0, c3 = 0, v = 0;
            if (idx < NB) {
                c0 = h4[0][idx]; c1 = h4[1][idx];
                c2 = h4[2][idx]; c3 = h4[3][idx];
                v = c0 + c1 + c2 + c3;
            }
            int s = v;
            #pragma unroll
            for (int off = 1; off < 64; off <<= 1) {
                int u = __shfl_up(s, off);
                if (tid >= off) s += u;
            }
            if (idx < NB) {
                int ex = carry + s - v;
                start[idx] = ex;
                tot[idx] = v;
                h4[0][idx] = ex;
                h4[1][idx] = ex + c0;
                h4[2][idx] = ex + c0 + c1;
                h4[3][idx] = ex + c0 + c1 + c2;
            }
            carry += __shfl(s, 63);
        }
    }
    __syncthreads();
    for (int i = tid; i < NB; i += 512) {   // reserve global runs
        int cnt = tot[i];
        int g = cnt ? atomicAdd(&gfill[i], cnt) : 0;
        dstoff[i] = g - start[i];
    }
    __syncthreads();
    for (int i = tid; i < BIN_CH; i += 512) {
        int e = e0 + i;
        if (e >= E) continue;
        int d = dst[e];
        int b = d >> 9;
        int slot = atomicAdd(&h4[grp][b], 1);         // block-local rank
        int gidx = b * C + dstoff[b] + slot;
        if (gidx < (b + 1) * C)
            binbuf[gidx] = (unsigned int)src[e] | ((unsigned int)(d & 511) << 17);
    }
}

// one block per bucket: split hist(4x512) -> scan -> rowptr/dinv -> place.
// Bucket base computed in-kernel (wave 1 sums gfill[0..b)).
__global__ __launch_bounds__(256) void build_kernel(
        const unsigned int* __restrict__ binbuf, const int* __restrict__ gfill,
        int* __restrict__ rowptr, float* __restrict__ dinv, int* __restrict__ col,
        int NB, int C, int N, int E) {
    __shared__ int h4[4][512];       // per-group counts -> cursors
    __shared__ int hs[512];          // exclusive scan of totals
    __shared__ int tot[512];
    __shared__ int bbase_s;
    int b = blockIdx.x, tid = threadIdx.x;
    int grp = tid >> 6;
    int cnt = gfill[b];
    const unsigned int* p = binbuf + (size_t)b * C;
    for (int i = tid; i < 4 * 512; i += 256) ((int*)h4)[i] = 0;
    __syncthreads();
    if (tid >= 64 && tid < 128) {          // wave 1: base = sum gfill[0..b)
        int l = tid - 64;
        int s = 0;
        for (int i = l; i < b; i += 64) s += gfill[i];
        #pragma unroll
        for (int off = 32; off > 0; off >>= 1) s += __shfl_down(s, off);
        if (l == 0) bbase_s = s;
    }
    for (int i = tid; i < cnt; i += 256) atomicAdd(&h4[grp][p[i] >> 17], 1);
    __syncthreads();
    if (tid < 64) {        // wave 0: totals, scan, per-group cursor bases
        int carry = 0;
        for (int base = 0; base < 512; base += 64) {
            int idx = base + tid;
            int c0 = h4[0][idx], c1 = h4[1][idx], c2 = h4[2][idx], c3 = h4[3][idx];
            int v = c0 + c1 + c2 + c3;
            int s = v;
            #pragma unroll
            for (int off = 1; off < 64; off <<= 1) {
                int u = __shfl_up(s, off);
                if (tid >= off) s += u;
            }
            int ex = carry + s - v;
            hs[idx] = ex;
            tot[idx] = v;
            h4[0][idx] = ex;
            h4[1][idx] = ex + c0;
            h4[2][idx] = ex + c0 + c1;
            h4[3][idx] = ex + c0 + c1 + c2;
            carry += __shfl(s, 63);
        }
    }
    __syncthreads();
    int base = bbase_s;
    for (int i = tid; i < 512; i += 256) {
        int node = b * 512 + i;
        if (node < N) {
            rowptr[node] = base + hs[i];
            dinv[node] = 1.0f / sqrtf((float)(tot[i] + 1));
        }
    }
    if (b == 0 && tid == 0) rowptr[N] = E;
    __syncthreads();
    for (int i = tid; i < cnt; i += 256) {  // place via per-group cursors
        unsigned int u = p[i];
        int local = u >> 17;
        int pos = atomicAdd(&h4[grp][local], 1);
        col[base + pos] = (int)(u & 0x1FFFFu);
    }
}

// ---- input layer: t' = fp8( dinv_i * (x @ W_s) ) --------------------------

__global__ void in_gemm_kernel(const float* __restrict__ x, const float* __restrict__ W,
                               const float* __restrict__ dinv,
                               unsigned char* __restrict__ t8, int n) {
    int g = blockIdx.x * 256 + threadIdx.x;
    int i = g >> 6, c2 = g & 63;
    if (i >= n) return;
    float x0 = x[i * 3], x1 = x[i * 3 + 1], x2 = x[i * 3 + 2];
    float d = dinv[i];
    int c = c2 * 2;
    float v0 = d * (x0 * W[c]     + x1 * W[128 + c]     + x2 * W[256 + c]);
    float v1 = d * (x0 * W[c + 1] + x1 * W[128 + c + 1] + x2 * W[256 + c + 1]);
    unsigned int pk = __builtin_amdgcn_cvt_pk_fp8_f32(v0, v1, 0, false);
    ((unsigned short*)t8)[(size_t)i * 64 + c2] = (unsigned short)(pk & 0xFFFF);
}

// ---- aggregation: out_i = relu( d_i * (t'_i + sum_j t'_j) + b ) -----------
// Quarter-per-node; 32-edge rounds: 16 uint4 row-loads in flight per wave.

__global__ __launch_bounds__(256) void agg_kernel(
        const unsigned char* __restrict__ t8, const int* __restrict__ rowptr,
        const int* __restrict__ col, const float* __restrict__ dinv,
        const float* __restrict__ bias, unsigned short* __restrict__ out, int n) {
    int node = blockIdx.x * 16 + (threadIdx.x >> 4);
    int lane = threadIdx.x & 63;
    int q16 = lane >> 4;            // quarter (node) within wave
    int lq  = lane & 15;            // edge slot within half-round
    int oct = (lane >> 3) & 1;      // which of 2 rows this lane helps load
    int l8  = lane & 7;             // 16B chunk within row
    if (node >= n) node = n - 1;    // dup work in tail, benign
    floatx2 acc[8];                 // cols 16*l8 .. +16
    #pragma unroll
    for (int i = 0; i < 8; ++i) acc[i] = (floatx2){0.f, 0.f};

    int beg = rowptr[node];
    int deg = rowptr[node + 1] - beg;
    for (int base = 0; base < deg; base += 32) {
        int m = deg - base;
        int jv0 = (lq < m)      ? col[beg + base + lq]      : n;   // n = zero row
        int jv1 = (lq + 16 < m) ? col[beg + base + 16 + lq] : n;
        uint4 v[16];
        #pragma unroll
        for (int q = 0; q < 8; ++q) {
            int j = __shfl(jv0, q16 * 16 + q * 2 + oct);
            v[q] = ((const uint4*)(t8 + (size_t)j * 128))[l8];
        }
        #pragma unroll
        for (int q = 0; q < 8; ++q) {
            int j = __shfl(jv1, q16 * 16 + q * 2 + oct);
            v[8 + q] = ((const uint4*)(t8 + (size_t)j * 128))[l8];
        }
        #pragma unroll
        for (int q = 0; q < 16; ++q) {
            acc[0] += __builtin_amdgcn_cvt_pk_f32_fp8(v[q].x, false);
            acc[1] += __builtin_amdgcn_cvt_pk_f32_fp8(v[q].x, true);
            acc[2] += __builtin_amdgcn_cvt_pk_f32_fp8(v[q].y, false);
            acc[3] += __builtin_amdgcn_cvt_pk_f32_fp8(v[q].y, true);
            acc[4] += __builtin_amdgcn_cvt_pk_f32_fp8(v[q].z, false);
            acc[5] += __builtin_amdgcn_cvt_pk_f32_fp8(v[q].z, true);
            acc[6] += __builtin_amdgcn_cvt_pk_f32_fp8(v[q].w, false);
            acc[7] += __builtin_amdgcn_cvt_pk_f32_fp8(v[q].w, true);
        }
    }
    #pragma unroll
    for (int i = 0; i < 8; ++i) {
        acc[i].x += __shfl_xor(acc[i].x, 8);
        acc[i].y += __shfl_xor(acc[i].y, 8);
    }
    uint4 s = ((const uint4*)(t8 + (size_t)node * 128))[l8];
    acc[0] += __builtin_amdgcn_cvt_pk_f32_fp8(s.x, false);
    acc[1] += __builtin_amdgcn_cvt_pk_f32_fp8(s.x, true);
    acc[2] += __builtin_amdgcn_cvt_pk_f32_fp8(s.y, false);
    acc[3] += __builtin_amdgcn_cvt_pk_f32_fp8(s.y, true);
    acc[4] += __builtin_amdgcn_cvt_pk_f32_fp8(s.z, false);
    acc[5] += __builtin_amdgcn_cvt_pk_f32_fp8(s.z, true);
    acc[6] += __builtin_amdgcn_cvt_pk_f32_fp8(s.w, false);
    acc[7] += __builtin_amdgcn_cvt_pk_f32_fp8(s.w, true);

    float di = dinv[node];
    const float4* b4 = (const float4*)bias;     // cols 16*l8 .. +16
    float o[16];
    #pragma unroll
    for (int k = 0; k < 4; ++k) {
        float4 bb = b4[l8 * 4 + k];
        o[k*4+0] = fmaxf(di * acc[k*2].x   + bb.x, 0.f);
        o[k*4+1] = fmaxf(di * acc[k*2].y   + bb.y, 0.f);
        o[k*4+2] = fmaxf(di * acc[k*2+1].x + bb.z, 0.f);
        o[k*4+3] = fmaxf(di * acc[k*2+1].y + bb.w, 0.f);
    }
    if (oct == 0) {
        uint4 w0, w1;
        w0.x = pk_bf(o[0],  o[1]);  w0.y = pk_bf(o[2],  o[3]);
        w0.z = pk_bf(o[4],  o[5]);  w0.w = pk_bf(o[6],  o[7]);
        w1.x = pk_bf(o[8],  o[9]);  w1.y = pk_bf(o[10], o[11]);
        w1.z = pk_bf(o[12], o[13]); w1.w = pk_bf(o[14], o[15]);
        ((uint4*)(out + (size_t)node * 128))[l8 * 2]     = w0;
        ((uint4*)(out + (size_t)node * 128))[l8 * 2 + 1] = w1;
    }
}

// ---- shared GEMM pieces ---------------------------------------------------

__device__ __forceinline__ void stage_ws(unsigned short* Ws, const unsigned short* Wp, int tid) {
    const int4* s = (const int4*)Wp;
    int4* d = (int4*)Ws;
    #pragma unroll
    for (int i = 0; i < 8; ++i) d[tid + 256 * i] = s[tid + 256 * i];
}

__device__ __forceinline__ void gemm_regs(const short8 af[2][4], const unsigned short* Ws,
                                          int lane, floatx4 acc[2][8]) {
    #pragma unroll
    for (int t = 0; t < 2; ++t)
        #pragma unroll
        for (int nt = 0; nt < 8; ++nt) acc[t][nt] = (floatx4){0.f, 0.f, 0.f, 0.f};
    #pragma unroll
    for (int kc = 0; kc < 4; ++kc) {
        #pragma unroll
        for (int nt = 0; nt < 8; ++nt) {
            short8 bf = *((const short8*)(Ws + ((kc * 8 + nt) * 64 + lane) * 8));
            acc[0][nt] = __builtin_amdgcn_mfma_f32_16x16x32_bf16(af[0][kc], bf, acc[0][nt], 0, 0, 0);
            acc[1][nt] = __builtin_amdgcn_mfma_f32_16x16x32_bf16(af[1][kc], bf, acc[1][nt], 0, 0, 0);
        }
    }
}

__device__ __forceinline__ void gemm_lds(const unsigned short* Hs, const unsigned short* Ws,
                                         int wav, int lane, floatx4 acc[2][8]) {
    int quad = lane >> 4, mrow = lane & 15;
    short8 af[2][4];
    #pragma unroll
    for (int t = 0; t < 2; ++t)
        #pragma unroll
        for (int kc = 0; kc < 4; ++kc)
            af[t][kc] = ld_frag(Hs + (wav * 32 + t * 16 + mrow) * HS_STRIDE + (kc * 4 + quad) * 8);
    gemm_regs(af, Ws, lane, acc);
}

__device__ __forceinline__ void relu_store_hs(
        unsigned short* Hs, const float* __restrict__ bias,
        floatx4 acc[2][8], int wav, int lane) {
    int quad = lane >> 4, mrow = lane & 15;
    #pragma unroll
    for (int t = 0; t < 2; ++t) {
        #pragma unroll
        for (int nt = 0; nt < 8; ++nt) {
            int colc = nt * 16 + mrow;
            float bcol = bias[colc];
            #pragma unroll
            for (int r = 0; r < 4; ++r) {
                int rowl = wav * 32 + t * 16 + quad * 4 + r;
                Hs[rowl * HS_STRIDE + colc] = f2bf(fmaxf(acc[t][nt][r] + bcol, 0.f));
            }
        }
    }
}

// ---- encoder GEMM: t8 = fp8( dinv[row] * (A@W) ) --------------------------

__global__ __launch_bounds__(256) void gemm_enc_kernel(
        const unsigned short* __restrict__ A, const unsigned short* __restrict__ Wp,
        const float* __restrict__ dinv, unsigned char* __restrict__ outp, int n) {
    __shared__ unsigned short Ws[16384];
    int tid = threadIdx.x;
    stage_ws(Ws, Wp, tid);
    int wave = tid >> 6, lane = tid & 63;
    int quad = lane >> 4, mrow = lane & 15;
    int row0 = blockIdx.x * 128 + wave * 32;

    short8 af[2][4];
    #pragma unroll
    for (int t = 0; t < 2; ++t) {
        int arow = row0 + t * 16 + mrow; if (arow >= n) arow = n - 1;
        const unsigned short* abase = A + (size_t)arow * 128 + quad * 8;
        #pragma unroll
        for (int kc = 0; kc < 4; ++kc)
            af[t][kc] = *((const short8*)(abase + kc * 32));
    }
    __syncthreads();
    floatx4 acc[2][8];
    gemm_regs(af, Ws, lane, acc);

    #pragma unroll
    for (int t = 0; t < 2; ++t) {
        int rbase = row0 + t * 16 + quad * 4;
        float dv[4];
        #pragma unroll
        for (int r = 0; r < 4; ++r)
            dv[r] = (rbase + r < n) ? dinv[rbase + r] : 0.f;
        #pragma unroll
        for (int nt = 0; nt < 8; ++nt) {
            int colc = nt * 16 + mrow;
            #pragma unroll
            for (int r = 0; r < 4; ++r) {
                int row = rbase + r;
                if (row < n)
                    outp[(size_t)row * 128 + colc] = f2fp8(acc[t][nt][r] * dv[r]);
            }
        }
    }
}

// ---- fused decoder: GEMM(W_sd) -> GEMM(W_md) -> GEMM(W_md)+proj+residual --

__global__ __launch_bounds__(256) void decoder_kernel(
        const unsigned short* __restrict__ A,
        const unsigned short* __restrict__ Wp_sd, const float* __restrict__ b_sd,
        const unsigned short* __restrict__ Wp_md, const float* __restrict__ b_md,
        const float* __restrict__ W_ed, const float* __restrict__ b_ed,
        const float* __restrict__ x, float* __restrict__ out, int n) {
    __shared__ unsigned short Ws[16384];
    __shared__ unsigned short Hs[128 * HS_STRIDE];
    int tid = threadIdx.x;
    stage_ws(Ws, Wp_sd, tid);
    int wav = tid >> 6, lane = tid & 63;
    int quad = lane >> 4, mrow = lane & 15;
    int row0 = blockIdx.x * 128 + wav * 32;

    short8 af[2][4];
    #pragma unroll
    for (int t = 0; t < 2; ++t) {
        int arow = row0 + t * 16 + mrow; if (arow >= n) arow = n - 1;
        const unsigned short* abase = A + (size_t)arow * 128 + quad * 8;
        #pragma unroll
        for (int kc = 0; kc < 4; ++kc)
            af[t][kc] = *((const short8*)(abase + kc * 32));
    }
    __syncthreads();

    floatx4 acc[2][8];
    // stage 1: h @ W_sd
    gemm_regs(af, Ws, lane, acc);
    relu_store_hs(Hs, b_sd, acc, wav, lane);
    __syncthreads();                 // all waves done reading Ws
    stage_ws(Ws, Wp_md, tid);
    __syncthreads();
    // stage 2: @ W_md (Hs rows are wave-private -> no barrier around store)
    gemm_lds(Hs, Ws, wav, lane, acc);
    relu_store_hs(Hs, b_md, acc, wav, lane);
    // stage 3: @ W_md
    gemm_lds(Hs, Ws, wav, lane, acc);

    // out-projection: relu(acc+b_md) @ W_ed + b_ed + x
    float wed[8][3];
    #pragma unroll
    for (int nt = 0; nt < 8; ++nt) {
        int c = nt * 16 + mrow;
        #pragma unroll
        for (int k = 0; k < 3; ++k) wed[nt][k] = W_ed[c * 3 + k];
    }
    #pragma unroll
    for (int t = 0; t < 2; ++t) {
        #pragma unroll
        for (int r = 0; r < 4; ++r) {
            float s0 = 0.f, s1 = 0.f, s2 = 0.f;
            #pragma unroll
            for (int nt = 0; nt < 8; ++nt) {
                float v = fmaxf(acc[t][nt][r] + b_md[nt * 16 + mrow], 0.f);
                s0 += v * wed[nt][0]; s1 += v * wed[nt][1]; s2 += v * wed[nt][2];
            }
            #pragma unroll
            for (int off = 1; off < 16; off <<= 1) {
                s0 += __shfl_xor(s0, off);
                s1 += __shfl_xor(s1, off);
                s2 += __shfl_xor(s2, off);
            }
            if (mrow == 0) {
                int row = row0 + t * 16 + quad * 4 + r;
                if (row < n) {
                    out[row * 3 + 0] = s0 + b_ed[0] + x[row * 3 + 0];
                    out[row * 3 + 1] = s1 + b_ed[1] + x[row * 3 + 1];
                    out[row * 3 + 2] = s2 + b_ed[2] + x[row * 3 + 2];
                }
            }
        }
    }
}

// ---------------------------------------------------------------------------

extern "C" void kernel_launch(void* const* d_in, const int* in_sizes, int n_in,
                              void* d_out, int out_size, void* d_ws, size_t ws_size,
                              hipStream_t stream) {
    const float* x    = (const float*)d_in[0];
    const int*   ei   = (const int*)d_in[1];
    const float* W_s  = (const float*)d_in[2];
    const float* b_s  = (const float*)d_in[3];
    const float* W_m  = (const float*)d_in[4];
    const float* b_m  = (const float*)d_in[5];
    const float* W_e  = (const float*)d_in[6];
    const float* b_e  = (const float*)d_in[7];
    const float* W_sd = (const float*)d_in[8];
    const float* b_sd = (const float*)d_in[9];
    const float* W_md = (const float*)d_in[10];
    const float* b_md = (const float*)d_in[11];
    const float* W_ed = (const float*)d_in[12];
    const float* b_ed = (const float*)d_in[13];
    float* outp = (float*)d_out;

    const int N = in_sizes[0] / 3;
    const int E = in_sizes[1] / 2;
    const int* src = ei;
    const int* dst = ei + E;

    const int NB = (N + 511) >> 9;                       // 512-node buckets
    const int C  = (((E / NB) * 3 / 2) + 255) & ~255;    // segment cap, 1.5x mean

    char* p = (char*)d_ws;
    auto carve = [&](size_t bytes) {
        void* r = (void*)p;
        p += (bytes + 255) & ~(size_t)255;
        return r;
    };
    int*   rowptr = (int*)  carve((size_t)(N + 1) * 4);
    int*   col    = (int*)  carve((size_t)E * 4);
    float* dinv   = (float*)carve((size_t)N * 4);
    int*   gfill  = (int*)  carve((size_t)NB * 4);
    unsigned int* binbuf = (unsigned int*)carve((size_t)NB * C * 4);
    unsigned short* Wp_m  = (unsigned short*)carve(16384 * 2);
    unsigned short* Wp_e  = (unsigned short*)carve(16384 * 2);
    unsigned short* Wp_sd = (unsigned short*)carve(16384 * 2);
    unsigned short* Wp_md = (unsigned short*)carve(16384 * 2);
    unsigned char*  T8 = (unsigned char*) carve((size_t)(N + 1) * 128);   // +1 zero row
    unsigned short* A  = (unsigned short*)carve((size_t)N * 128 * 2);
    (void)ws_size;

    const int gBin = (E + BIN_CH - 1) / BIN_CH;
    const int gNode16 = (N + 15) / 16;
    const int gRow128 = (N + 127) / 128;

    // weight packs + buffer init (no deps)
    pack_kernel<<<32, 256, 0, stream>>>(W_m, W_e, W_sd, W_md, Wp_m, Wp_e, Wp_sd, Wp_md,
                                        gfill, T8 + (size_t)N * 128, NB);

    // graph build
    bin_kernel<<<gBin, 512, 0, stream>>>(src, dst, gfill, binbuf, NB, C, E);
    build_kernel<<<NB, 256, 0, stream>>>(binbuf, gfill, rowptr, dinv, col, NB, C, N, E);

    // encoder (t' in fp8, h in bf16)
    in_gemm_kernel<<<(N * 64 + 255) / 256, 256, 0, stream>>>(x, W_s, dinv, T8, N);
    agg_kernel<<<gNode16, 256, 0, stream>>>(T8, rowptr, col, dinv, b_s, A, N);
    gemm_enc_kernel<<<gRow128, 256, 0, stream>>>(A, Wp_m, dinv, T8, N);
    agg_kernel<<<gNode16, 256, 0, stream>>>(T8, rowptr, col, dinv, b_m, A, N);
    gemm_enc_kernel<<<gRow128, 256, 0, stream>>>(A, Wp_m, dinv, T8, N);
    agg_kernel<<<gNode16, 256, 0, stream>>>(T8, rowptr, col, dinv, b_m, A, N);
    gemm_enc_kernel<<<gRow128, 256, 0, stream>>>(A, Wp_e, dinv, T8, N);
    agg_kernel<<<gNode16, 256, 0, stream>>>(T8, rowptr, col, dinv, b_e, A, N);

    // fused decoder
    decoder_kernel<<<gRow128, 256, 0, stream>>>(A, Wp_sd, b_sd, Wp_md, b_md,
                                                W_ed, b_ed, x, outp, N);
}

// Round 16
// 391.147 us; speedup vs baseline: 1.0664x; 1.0180x over previous
//
#include <hip/hip_runtime.h>

// ---------------------------------------------------------------------------
// GCN encoder (4 conv layers, shared CSR graph) + 3-layer MLP decoder.
// Round 16: 256-node buckets (NB=391) — build_kernel grid doubles (was
// block-count-starved at 196 blocks / 256 CUs). Rest = round 15.
// ---------------------------------------------------------------------------

typedef __attribute__((ext_vector_type(8))) short short8;
typedef __attribute__((ext_vector_type(4))) float floatx4;
typedef __attribute__((ext_vector_type(2))) float floatx2;

#define BIN_CH 8192          // edges per bin block
#define NBMAX 512            // max buckets supported
#define BKT 256              // nodes per bucket
#define HS_STRIDE 68         // LDS row stride in ushorts (136 B)

__device__ __forceinline__ unsigned short f2bf(float f) {
    unsigned int u = __float_as_uint(f);
    u += 0x7fffu + ((u >> 16) & 1u);          // round-to-nearest-even
    return (unsigned short)(u >> 16);
}
__device__ __forceinline__ unsigned int pk_bf(float a, float b) {
    return (unsigned int)f2bf(a) | ((unsigned int)f2bf(b) << 16);
}
__device__ __forceinline__ unsigned char f2fp8(float f) {
    return (unsigned char)(__builtin_amdgcn_cvt_pk_fp8_f32(f, f, 0, false) & 0xFF);
}
__device__ __forceinline__ short8 ld_frag(const unsigned short* p) {
    uint2 a = *(const uint2*)p;
    uint2 b = *(const uint2*)(p + 4);
    int4 v = make_int4((int)a.x, (int)a.y, (int)b.x, (int)b.y);
    return __builtin_bit_cast(short8, v);
}

// ---- weight pre-pack + buffer init (runs first) ---------------------------

__global__ void pack_kernel(const float* __restrict__ W0, const float* __restrict__ W1,
                            const float* __restrict__ W2, const float* __restrict__ W3,
                            unsigned short* __restrict__ P0, unsigned short* __restrict__ P1,
                            unsigned short* __restrict__ P2, unsigned short* __restrict__ P3,
                            int* __restrict__ gfill, unsigned char* __restrict__ t8zrow,
                            int NB) {
    if (blockIdx.x == 0) {                       // fold the memsets
        for (int i = threadIdx.x; i < NB; i += 256) gfill[i] = 0;
        if (threadIdx.x < 32) ((unsigned int*)t8zrow)[threadIdx.x] = 0;
    }
    int which = blockIdx.x >> 3;
    const float* W = which == 0 ? W0 : which == 1 ? W1 : which == 2 ? W2 : W3;
    unsigned short* P = which == 0 ? P0 : which == 1 ? P1 : which == 2 ? P2 : P3;
    int f = (blockIdx.x & 7) * 256 + threadIdx.x;
    int lane = f & 63, nt = (f >> 6) & 7, kc = f >> 9;
    int kbase = kc * 32 + (lane >> 4) * 8;
    int ncol = nt * 16 + (lane & 15);
    short8 frag;
    #pragma unroll
    for (int j = 0; j < 8; ++j)
        frag[j] = (short)f2bf(W[(size_t)(kbase + j) * 128 + ncol]);
    *((short8*)(P + (size_t)f * 8)) = frag;
}

// ---- graph build ----------------------------------------------------------
// entry = (d & 255) << 17 | src   (src < 2^17)

__global__ __launch_bounds__(512) void bin_kernel(
        const int* __restrict__ src, const int* __restrict__ dst,
        int* __restrict__ gfill, unsigned int* __restrict__ binbuf,
        int NB, int C, int E) {
    __shared__ int h4[4][NBMAX];     // per-group counts -> cursors
    __shared__ int start[NBMAX];
    __shared__ int tot[NBMAX];
    __shared__ int dstoff[NBMAX];
    int tid = threadIdx.x;
    int grp = tid >> 7;
    int e0 = blockIdx.x * BIN_CH;
    for (int i = tid; i < 4 * NBMAX; i += 512) ((int*)h4)[i] = 0;
    __syncthreads();
    for (int i = tid; i < BIN_CH; i += 512) {
        int e = e0 + i;
        if (e < E) atomicAdd(&h4[grp][dst[e] >> 8], 1);
    }
    __syncthreads();
    if (tid < 64) {        // wave 0: totals, exclusive scan, per-group bases
        int carry = 0;
        for (int base = 0; base < NB; base += 64) {
            int idx = base + tid;
            int c0 = 0, c1 = 0, c2 = 0, c3 = 0, v = 0;
            if (idx < NB) {
                c0 = h4[0][idx]; c1 = h4[1][idx];
                c2 = h4[2][idx]; c3 = h4[3][idx];
                v = c0 + c1 + c2 + c3;
            }
            int s = v;
            #pragma unroll
            for (int off = 1; off < 64; off <<= 1) {
                int u = __shfl_up(s, off);
                if (tid >= off) s += u;
            }
            if (idx < NB) {
                int ex = carry + s - v;
                start[idx] = ex;
                tot[idx] = v;
                h4[0][idx] = ex;
                h4[1][idx] = ex + c0;
                h4[2][idx] = ex + c0 + c1;
                h4[3][idx] = ex + c0 + c1 + c2;
            }
            carry += __shfl(s, 63);
        }
    }
    __syncthreads();
    for (int i = tid; i < NB; i += 512) {   // reserve global runs
        int cnt = tot[i];
        int g = cnt ? atomicAdd(&gfill[i], cnt) : 0;
        dstoff[i] = g - start[i];
    }
    __syncthreads();
    for (int i = tid; i < BIN_CH; i += 512) {
        int e = e0 + i;
        if (e >= E) continue;
        int d = dst[e];
        int b = d >> 8;
        int slot = atomicAdd(&h4[grp][b], 1);         // block-local rank
        int gidx = b * C + dstoff[b] + slot;
        if (gidx < (b + 1) * C)
            binbuf[gidx] = (unsigned int)src[e] | ((unsigned int)(d & 255) << 17);
    }
}

// one block per bucket: split hist(4x256) -> scan -> rowptr/dinv -> place.
// Bucket base computed in-kernel (wave 1 sums gfill[0..b)).
__global__ __launch_bounds__(256) void build_kernel(
        const unsigned int* __restrict__ binbuf, const int* __restrict__ gfill,
        int* __restrict__ rowptr, float* __restrict__ dinv, int* __restrict__ col,
        int NB, int C, int N, int E) {
    __shared__ int h4[4][BKT];       // per-group counts -> cursors
    __shared__ int hs[BKT];          // exclusive scan of totals
    __shared__ int tot[BKT];
    __shared__ int bbase_s;
    int b = blockIdx.x, tid = threadIdx.x;
    int grp = tid >> 6;
    int cnt = gfill[b];
    const unsigned int* p = binbuf + (size_t)b * C;
    for (int i = tid; i < 4 * BKT; i += 256) ((int*)h4)[i] = 0;
    __syncthreads();
    if (tid >= 64 && tid < 128) {          // wave 1: base = sum gfill[0..b)
        int l = tid - 64;
        int s = 0;
        for (int i = l; i < b; i += 64) s += gfill[i];
        #pragma unroll
        for (int off = 32; off > 0; off >>= 1) s += __shfl_down(s, off);
        if (l == 0) bbase_s = s;
    }
    for (int i = tid; i < cnt; i += 256) atomicAdd(&h4[grp][p[i] >> 17], 1);
    __syncthreads();
    if (tid < 64) {        // wave 0: totals, scan, per-group cursor bases
        int carry = 0;
        for (int base = 0; base < BKT; base += 64) {
            int idx = base + tid;
            int c0 = h4[0][idx], c1 = h4[1][idx], c2 = h4[2][idx], c3 = h4[3][idx];
            int v = c0 + c1 + c2 + c3;
            int s = v;
            #pragma unroll
            for (int off = 1; off < 64; off <<= 1) {
                int u = __shfl_up(s, off);
                if (tid >= off) s += u;
            }
            int ex = carry + s - v;
            hs[idx] = ex;
            tot[idx] = v;
            h4[0][idx] = ex;
            h4[1][idx] = ex + c0;
            h4[2][idx] = ex + c0 + c1;
            h4[3][idx] = ex + c0 + c1 + c2;
            carry += __shfl(s, 63);
        }
    }
    __syncthreads();
    int base = bbase_s;
    if (tid < BKT) {
        int node = b * BKT + tid;
        if (node < N) {
            rowptr[node] = base + hs[tid];
            dinv[node] = 1.0f / sqrtf((float)(tot[tid] + 1));
        }
    }
    if (b == 0 && tid == 0) rowptr[N] = E;
    __syncthreads();
    for (int i = tid; i < cnt; i += 256) {  // place via per-group cursors
        unsigned int u = p[i];
        int local = u >> 17;
        int pos = atomicAdd(&h4[grp][local], 1);
        col[base + pos] = (int)(u & 0x1FFFFu);
    }
}

// ---- input layer: t' = fp8( dinv_i * (x @ W_s) ) --------------------------

__global__ void in_gemm_kernel(const float* __restrict__ x, const float* __restrict__ W,
                               const float* __restrict__ dinv,
                               unsigned char* __restrict__ t8, int n) {
    int g = blockIdx.x * 256 + threadIdx.x;
    int i = g >> 6, c2 = g & 63;
    if (i >= n) return;
    float x0 = x[i * 3], x1 = x[i * 3 + 1], x2 = x[i * 3 + 2];
    float d = dinv[i];
    int c = c2 * 2;
    float v0 = d * (x0 * W[c]     + x1 * W[128 + c]     + x2 * W[256 + c]);
    float v1 = d * (x0 * W[c + 1] + x1 * W[128 + c + 1] + x2 * W[256 + c + 1]);
    unsigned int pk = __builtin_amdgcn_cvt_pk_fp8_f32(v0, v1, 0, false);
    ((unsigned short*)t8)[(size_t)i * 64 + c2] = (unsigned short)(pk & 0xFFFF);
}

// ---- aggregation: out_i = relu( d_i * (t'_i + sum_j t'_j) + b ) -----------
// Quarter-per-node; 32-edge rounds: 16 uint4 row-loads in flight per wave.

__global__ __launch_bounds__(256) void agg_kernel(
        const unsigned char* __restrict__ t8, const int* __restrict__ rowptr,
        const int* __restrict__ col, const float* __restrict__ dinv,
        const float* __restrict__ bias, unsigned short* __restrict__ out, int n) {
    int node = blockIdx.x * 16 + (threadIdx.x >> 4);
    int lane = threadIdx.x & 63;
    int q16 = lane >> 4;            // quarter (node) within wave
    int lq  = lane & 15;            // edge slot within half-round
    int oct = (lane >> 3) & 1;      // which of 2 rows this lane helps load
    int l8  = lane & 7;             // 16B chunk within row
    if (node >= n) node = n - 1;    // dup work in tail, benign
    floatx2 acc[8];                 // cols 16*l8 .. +16
    #pragma unroll
    for (int i = 0; i < 8; ++i) acc[i] = (floatx2){0.f, 0.f};

    int beg = rowptr[node];
    int deg = rowptr[node + 1] - beg;
    for (int base = 0; base < deg; base += 32) {
        int m = deg - base;
        int jv0 = (lq < m)      ? col[beg + base + lq]      : n;   // n = zero row
        int jv1 = (lq + 16 < m) ? col[beg + base + 16 + lq] : n;
        uint4 v[16];
        #pragma unroll
        for (int q = 0; q < 8; ++q) {
            int j = __shfl(jv0, q16 * 16 + q * 2 + oct);
            v[q] = ((const uint4*)(t8 + (size_t)j * 128))[l8];
        }
        #pragma unroll
        for (int q = 0; q < 8; ++q) {
            int j = __shfl(jv1, q16 * 16 + q * 2 + oct);
            v[8 + q] = ((const uint4*)(t8 + (size_t)j * 128))[l8];
        }
        #pragma unroll
        for (int q = 0; q < 16; ++q) {
            acc[0] += __builtin_amdgcn_cvt_pk_f32_fp8(v[q].x, false);
            acc[1] += __builtin_amdgcn_cvt_pk_f32_fp8(v[q].x, true);
            acc[2] += __builtin_amdgcn_cvt_pk_f32_fp8(v[q].y, false);
            acc[3] += __builtin_amdgcn_cvt_pk_f32_fp8(v[q].y, true);
            acc[4] += __builtin_amdgcn_cvt_pk_f32_fp8(v[q].z, false);
            acc[5] += __builtin_amdgcn_cvt_pk_f32_fp8(v[q].z, true);
            acc[6] += __builtin_amdgcn_cvt_pk_f32_fp8(v[q].w, false);
            acc[7] += __builtin_amdgcn_cvt_pk_f32_fp8(v[q].w, true);
        }
    }
    #pragma unroll
    for (int i = 0; i < 8; ++i) {
        acc[i].x += __shfl_xor(acc[i].x, 8);
        acc[i].y += __shfl_xor(acc[i].y, 8);
    }
    uint4 s = ((const uint4*)(t8 + (size_t)node * 128))[l8];
    acc[0] += __builtin_amdgcn_cvt_pk_f32_fp8(s.x, false);
    acc[1] += __builtin_amdgcn_cvt_pk_f32_fp8(s.x, true);
    acc[2] += __builtin_amdgcn_cvt_pk_f32_fp8(s.y, false);
    acc[3] += __builtin_amdgcn_cvt_pk_f32_fp8(s.y, true);
    acc[4] += __builtin_amdgcn_cvt_pk_f32_fp8(s.z, false);
    acc[5] += __builtin_amdgcn_cvt_pk_f32_fp8(s.z, true);
    acc[6] += __builtin_amdgcn_cvt_pk_f32_fp8(s.w, false);
    acc[7] += __builtin_amdgcn_cvt_pk_f32_fp8(s.w, true);

    float di = dinv[node];
    const float4* b4 = (const float4*)bias;     // cols 16*l8 .. +16
    float o[16];
    #pragma unroll
    for (int k = 0; k < 4; ++k) {
        float4 bb = b4[l8 * 4 + k];
        o[k*4+0] = fmaxf(di * acc[k*2].x   + bb.x, 0.f);
        o[k*4+1] = fmaxf(di * acc[k*2].y   + bb.y, 0.f);
        o[k*4+2] = fmaxf(di * acc[k*2+1].x + bb.z, 0.f);
        o[k*4+3] = fmaxf(di * acc[k*2+1].y + bb.w, 0.f);
    }
    if (oct == 0) {
        uint4 w0, w1;
        w0.x = pk_bf(o[0],  o[1]);  w0.y = pk_bf(o[2],  o[3]);
        w0.z = pk_bf(o[4],  o[5]);  w0.w = pk_bf(o[6],  o[7]);
        w1.x = pk_bf(o[8],  o[9]);  w1.y = pk_bf(o[10], o[11]);
        w1.z = pk_bf(o[12], o[13]); w1.w = pk_bf(o[14], o[15]);
        ((uint4*)(out + (size_t)node * 128))[l8 * 2]     = w0;
        ((uint4*)(out + (size_t)node * 128))[l8 * 2 + 1] = w1;
    }
}

// ---- shared GEMM pieces ---------------------------------------------------

__device__ __forceinline__ void stage_ws(unsigned short* Ws, const unsigned short* Wp, int tid) {
    const int4* s = (const int4*)Wp;
    int4* d = (int4*)Ws;
    #pragma unroll
    for (int i = 0; i < 8; ++i) d[tid + 256 * i] = s[tid + 256 * i];
}

__device__ __forceinline__ void gemm_regs(const short8 af[2][4], const unsigned short* Ws,
                                          int lane, floatx4 acc[2][8]) {
    #pragma unroll
    for (int t = 0; t < 2; ++t)
        #pragma unroll
        for (int nt = 0; nt < 8; ++nt) acc[t][nt] = (floatx4){0.f, 0.f, 0.f, 0.f};
    #pragma unroll
    for (int kc = 0; kc < 4; ++kc) {
        #pragma unroll
        for (int nt = 0; nt < 8; ++nt) {
            short8 bf = *((const short8*)(Ws + ((kc * 8 + nt) * 64 + lane) * 8));
            acc[0][nt] = __builtin_amdgcn_mfma_f32_16x16x32_bf16(af[0][kc], bf, acc[0][nt], 0, 0, 0);
            acc[1][nt] = __builtin_amdgcn_mfma_f32_16x16x32_bf16(af[1][kc], bf, acc[1][nt], 0, 0, 0);
        }
    }
}

__device__ __forceinline__ void gemm_lds(const unsigned short* Hs, const unsigned short* Ws,
                                         int wav, int lane, floatx4 acc[2][8]) {
    int quad = lane >> 4, mrow = lane & 15;
    short8 af[2][4];
    #pragma unroll
    for (int t = 0; t < 2; ++t)
        #pragma unroll
        for (int kc = 0; kc < 4; ++kc)
            af[t][kc] = ld_frag(Hs + (wav * 32 + t * 16 + mrow) * HS_STRIDE + (kc * 4 + quad) * 8);
    gemm_regs(af, Ws, lane, acc);
}

__device__ __forceinline__ void relu_store_hs(
        unsigned short* Hs, const float* __restrict__ bias,
        floatx4 acc[2][8], int wav, int lane) {
    int quad = lane >> 4, mrow = lane & 15;
    #pragma unroll
    for (int t = 0; t < 2; ++t) {
        #pragma unroll
        for (int nt = 0; nt < 8; ++nt) {
            int colc = nt * 16 + mrow;
            float bcol = bias[colc];
            #pragma unroll
            for (int r = 0; r < 4; ++r) {
                int rowl = wav * 32 + t * 16 + quad * 4 + r;
                Hs[rowl * HS_STRIDE + colc] = f2bf(fmaxf(acc[t][nt][r] + bcol, 0.f));
            }
        }
    }
}

// ---- encoder GEMM: t8 = fp8( dinv[row] * (A@W) ) --------------------------

__global__ __launch_bounds__(256) void gemm_enc_kernel(
        const unsigned short* __restrict__ A, const unsigned short* __restrict__ Wp,
        const float* __restrict__ dinv, unsigned char* __restrict__ outp, int n) {
    __shared__ unsigned short Ws[16384];
    int tid = threadIdx.x;
    stage_ws(Ws, Wp, tid);
    int wave = tid >> 6, lane = tid & 63;
    int quad = lane >> 4, mrow = lane & 15;
    int row0 = blockIdx.x * 128 + wave * 32;

    short8 af[2][4];
    #pragma unroll
    for (int t = 0; t < 2; ++t) {
        int arow = row0 + t * 16 + mrow; if (arow >= n) arow = n - 1;
        const unsigned short* abase = A + (size_t)arow * 128 + quad * 8;
        #pragma unroll
        for (int kc = 0; kc < 4; ++kc)
            af[t][kc] = *((const short8*)(abase + kc * 32));
    }
    __syncthreads();
    floatx4 acc[2][8];
    gemm_regs(af, Ws, lane, acc);

    #pragma unroll
    for (int t = 0; t < 2; ++t) {
        int rbase = row0 + t * 16 + quad * 4;
        float dv[4];
        #pragma unroll
        for (int r = 0; r < 4; ++r)
            dv[r] = (rbase + r < n) ? dinv[rbase + r] : 0.f;
        #pragma unroll
        for (int nt = 0; nt < 8; ++nt) {
            int colc = nt * 16 + mrow;
            #pragma unroll
            for (int r = 0; r < 4; ++r) {
                int row = rbase + r;
                if (row < n)
                    outp[(size_t)row * 128 + colc] = f2fp8(acc[t][nt][r] * dv[r]);
            }
        }
    }
}

// ---- fused decoder: GEMM(W_sd) -> GEMM(W_md) -> GEMM(W_md)+proj+residual --

__global__ __launch_bounds__(256) void decoder_kernel(
        const unsigned short* __restrict__ A,
        const unsigned short* __restrict__ Wp_sd, const float* __restrict__ b_sd,
        const unsigned short* __restrict__ Wp_md, const float* __restrict__ b_md,
        const float* __restrict__ W_ed, const float* __restrict__ b_ed,
        const float* __restrict__ x, float* __restrict__ out, int n) {
    __shared__ unsigned short Ws[16384];
    __shared__ unsigned short Hs[128 * HS_STRIDE];
    int tid = threadIdx.x;
    stage_ws(Ws, Wp_sd, tid);
    int wav = tid >> 6, lane = tid & 63;
    int quad = lane >> 4, mrow = lane & 15;
    int row0 = blockIdx.x * 128 + wav * 32;

    short8 af[2][4];
    #pragma unroll
    for (int t = 0; t < 2; ++t) {
        int arow = row0 + t * 16 + mrow; if (arow >= n) arow = n - 1;
        const unsigned short* abase = A + (size_t)arow * 128 + quad * 8;
        #pragma unroll
        for (int kc = 0; kc < 4; ++kc)
            af[t][kc] = *((const short8*)(abase + kc * 32));
    }
    __syncthreads();

    floatx4 acc[2][8];
    // stage 1: h @ W_sd
    gemm_regs(af, Ws, lane, acc);
    relu_store_hs(Hs, b_sd, acc, wav, lane);
    __syncthreads();                 // all waves done reading Ws
    stage_ws(Ws, Wp_md, tid);
    __syncthreads();
    // stage 2: @ W_md (Hs rows are wave-private -> no barrier around store)
    gemm_lds(Hs, Ws, wav, lane, acc);
    relu_store_hs(Hs, b_md, acc, wav, lane);
    // stage 3: @ W_md
    gemm_lds(Hs, Ws, wav, lane, acc);

    // out-projection: relu(acc+b_md) @ W_ed + b_ed + x
    float wed[8][3];
    #pragma unroll
    for (int nt = 0; nt < 8; ++nt) {
        int c = nt * 16 + mrow;
        #pragma unroll
        for (int k = 0; k < 3; ++k) wed[nt][k] = W_ed[c * 3 + k];
    }
    #pragma unroll
    for (int t = 0; t < 2; ++t) {
        #pragma unroll
        for (int r = 0; r < 4; ++r) {
            float s0 = 0.f, s1 = 0.f, s2 = 0.f;
            #pragma unroll
            for (int nt = 0; nt < 8; ++nt) {
                float v = fmaxf(acc[t][nt][r] + b_md[nt * 16 + mrow], 0.f);
                s0 += v * wed[nt][0]; s1 += v * wed[nt][1]; s2 += v * wed[nt][2];
            }
            #pragma unroll
            for (int off = 1; off < 16; off <<= 1) {
                s0 += __shfl_xor(s0, off);
                s1 += __shfl_xor(s1, off);
                s2 += __shfl_xor(s2, off);
            }
            if (mrow == 0) {
                int row = row0 + t * 16 + quad * 4 + r;
                if (row < n) {
                    out[row * 3 + 0] = s0 + b_ed[0] + x[row * 3 + 0];
                    out[row * 3 + 1] = s1 + b_ed[1] + x[row * 3 + 1];
                    out[row * 3 + 2] = s2 + b_ed[2] + x[row * 3 + 2];
                }
            }
        }
    }
}

// ---------------------------------------------------------------------------

extern "C" void kernel_launch(void* const* d_in, const int* in_sizes, int n_in,
                              void* d_out, int out_size, void* d_ws, size_t ws_size,
                              hipStream_t stream) {
    const float* x    = (const float*)d_in[0];
    const int*   ei   = (const int*)d_in[1];
    const float* W_s  = (const float*)d_in[2];
    const float* b_s  = (const float*)d_in[3];
    const float* W_m  = (const float*)d_in[4];
    const float* b_m  = (const float*)d_in[5];
    const float* W_e  = (const float*)d_in[6];
    const float* b_e  = (const float*)d_in[7];
    const float* W_sd = (const float*)d_in[8];
    const float* b_sd = (const float*)d_in[9];
    const float* W_md = (const float*)d_in[10];
    const float* b_md = (const float*)d_in[11];
    const float* W_ed = (const float*)d_in[12];
    const float* b_ed = (const float*)d_in[13];
    float* outp = (float*)d_out;

    const int N = in_sizes[0] / 3;
    const int E = in_sizes[1] / 2;
    const int* src = ei;
    const int* dst = ei + E;

    const int NB = (N + BKT - 1) / BKT;                  // 256-node buckets
    const int C  = (((E / NB) * 3 / 2) + 255) & ~255;    // segment cap, 1.5x mean

    char* p = (char*)d_ws;
    auto carve = [&](size_t bytes) {
        void* r = (void*)p;
        p += (bytes + 255) & ~(size_t)255;
        return r;
    };
    int*   rowptr = (int*)  carve((size_t)(N + 1) * 4);
    int*   col    = (int*)  carve((size_t)E * 4);
    float* dinv   = (float*)carve((size_t)N * 4);
    int*   gfill  = (int*)  carve((size_t)NB * 4);
    unsigned int* binbuf = (unsigned int*)carve((size_t)NB * C * 4);
    unsigned short* Wp_m  = (unsigned short*)carve(16384 * 2);
    unsigned short* Wp_e  = (unsigned short*)carve(16384 * 2);
    unsigned short* Wp_sd = (unsigned short*)carve(16384 * 2);
    unsigned short* Wp_md = (unsigned short*)carve(16384 * 2);
    unsigned char*  T8 = (unsigned char*) carve((size_t)(N + 1) * 128);   // +1 zero row
    unsigned short* A  = (unsigned short*)carve((size_t)N * 128 * 2);
    (void)ws_size;

    const int gBin = (E + BIN_CH - 1) / BIN_CH;
    const int gNode16 = (N + 15) / 16;
    const int gRow128 = (N + 127) / 128;

    // weight packs + buffer init (no deps)
    pack_kernel<<<32, 256, 0, stream>>>(W_m, W_e, W_sd, W_md, Wp_m, Wp_e, Wp_sd, Wp_md,
                                        gfill, T8 + (size_t)N * 128, NB);

    // graph build
    bin_kernel<<<gBin, 512, 0, stream>>>(src, dst, gfill, binbuf, NB, C, E);
    build_kernel<<<NB, 256, 0, stream>>>(binbuf, gfill, rowptr, dinv, col, NB, C, N, E);

    // encoder (t' in fp8, h in bf16)
    in_gemm_kernel<<<(N * 64 + 255) / 256, 256, 0, stream>>>(x, W_s, dinv, T8, N);
    agg_kernel<<<gNode16, 256, 0, stream>>>(T8, rowptr, col, dinv, b_s, A, N);
    gemm_enc_kernel<<<gRow128, 256, 0, stream>>>(A, Wp_m, dinv, T8, N);
    agg_kernel<<<gNode16, 256, 0, stream>>>(T8, rowptr, col, dinv, b_m, A, N);
    gemm_enc_kernel<<<gRow128, 256, 0, stream>>>(A, Wp_m, dinv, T8, N);
    agg_kernel<<<gNode16, 256, 0, stream>>>(T8, rowptr, col, dinv, b_m, A, N);
    gemm_enc_kernel<<<gRow128, 256, 0, stream>>>(A, Wp_e, dinv, T8, N);
    agg_kernel<<<gNode16, 256, 0, stream>>>(T8, rowptr, col, dinv, b_e, A, N);

    // fused decoder
    decoder_kernel<<<gRow128, 256, 0, stream>>>(A, Wp_sd, b_sd, Wp_md, b_md,
                                                W_ed, b_ed, x, outp, N);
}